// Round 1
// baseline (416.490 us; speedup 1.0000x reference)
//
#include <hip/hip_runtime.h>

typedef unsigned short u16;
typedef unsigned int u32;
typedef unsigned long long u64;
typedef float f32x4 __attribute__((ext_vector_type(4)));
typedef __bf16 bf16x8 __attribute__((ext_vector_type(8)));
typedef u16 u16x8 __attribute__((ext_vector_type(8)));

#define DEV __device__ __forceinline__

// ---- constants for this problem ----
// B=4, T=1296 (36x36 patches), E=768, H=12, HD=64, M = B*T = 5184
// patch K = C_IN*P*P = 3*16*16 = 768

DEV u16 f2bf(float f) {
    union { float f; u32 u; } un; un.f = f;
    u32 u = un.u;
    return (u16)((u + 0x7fffu + ((u >> 16) & 1u)) >> 16);
}

DEV void gll16(const u16* src, u16* dst) {
    auto g = (const __attribute__((address_space(1))) u32*)(src);
    auto s = (__attribute__((address_space(3))) u32*)(dst);
    __builtin_amdgcn_global_load_lds(g, s, 16, 0, 0);
}

// ---------------- weight convert / transpose ----------------
__global__ void convcvt_k(const float* __restrict__ src, u16* __restrict__ dst) {
    int i = blockIdx.x * 256 + threadIdx.x;          // one float4 per thread
    f32x4 v = ((const f32x4*)src)[i];
    union { u16 q[4]; u64 ll; } un;
    #pragma unroll
    for (int j = 0; j < 4; ++j) un.q[j] = f2bf(v[j]);
    ((u64*)dst)[i] = un.ll;
}

// src: f32 [K][N] row-major; dst: bf16 [N][K]
__global__ void wtrans_k(const float* __restrict__ src, u16* __restrict__ dst, int K, int N) {
    __shared__ float tile[32][33];
    int n0 = blockIdx.x * 32, k0 = blockIdx.y * 32;
    int tx = threadIdx.x & 31, ty = threadIdx.x >> 5;   // 32 x 8
    #pragma unroll
    for (int i = 0; i < 32; i += 8)
        tile[ty + i][tx] = src[(size_t)(k0 + ty + i) * N + n0 + tx];
    __syncthreads();
    #pragma unroll
    for (int i = 0; i < 32; i += 8)
        dst[(size_t)(n0 + ty + i) * K + k0 + tx] = f2bf(tile[tx][ty + i]);
}

// ---------------- patch gather: x (B,3,576,576) -> A [5184][768] bf16 ----------------
__global__ void patch_k(const float* __restrict__ x, u16* __restrict__ out) {
    int idx = blockIdx.x * 256 + threadIdx.x;   // [b][c][i][p][j], j innermost
    int j = idx % 36; int r1 = idx / 36;
    int p = r1 % 16;  int r2 = r1 / 16;
    int i = r2 % 36;  int r3 = r2 / 36;
    int c = r3 % 3;   int b = r3 / 3;
    const f32x4* src = (const f32x4*)(x + (size_t)((b * 3 + c) * 576 + i * 16 + p) * 576 + j * 16);
    u16x8 lo, hi;
    #pragma unroll
    for (int k = 0; k < 2; ++k) {
        f32x4 v = src[k];
        #pragma unroll
        for (int e = 0; e < 4; ++e) lo[k * 4 + e] = f2bf(v[e]);
    }
    #pragma unroll
    for (int k = 0; k < 2; ++k) {
        f32x4 v = src[2 + k];
        #pragma unroll
        for (int e = 0; e < 4; ++e) hi[k * 4 + e] = f2bf(v[e]);
    }
    u16* dst = out + (size_t)(b * 1296 + i * 36 + j) * 768 + c * 256 + p * 16;
    *(u16x8*)dst = lo;
    *(u16x8*)(dst + 8) = hi;
}

// ---------------- LayerNorm: f32 [5184][768] -> bf16 [5184][768] ----------------
__global__ __launch_bounds__(256) void ln_k(const float* __restrict__ x, const float* __restrict__ g,
                                            const float* __restrict__ bta, u16* __restrict__ out) {
    int row = blockIdx.x * 4 + (threadIdx.x >> 6);
    int l = threadIdx.x & 63;
    const float* xr = x + (size_t)row * 768;
    float v[12]; float s = 0.f, s2 = 0.f;
    #pragma unroll
    for (int i = 0; i < 12; ++i) { v[i] = xr[l + 64 * i]; s += v[i]; s2 += v[i] * v[i]; }
    #pragma unroll
    for (int off = 32; off; off >>= 1) { s += __shfl_xor(s, off); s2 += __shfl_xor(s2, off); }
    float mu = s * (1.f / 768.f);
    float var = s2 * (1.f / 768.f) - mu * mu;
    float rs = rsqrtf(var + 1e-5f);
    u16* orow = out + (size_t)row * 768;
    #pragma unroll
    for (int i = 0; i < 12; ++i) {
        int c = l + 64 * i;
        orow[c] = f2bf((v[i] - mu) * rs * g[c] + bta[c]);
    }
}

// ---------------- V transpose: qkv[.][1536+h*64+d] -> vt[bh][d][t] (t padded to 1312) ----------------
__global__ void vtrans_k(const u16* __restrict__ qkv, u16* __restrict__ vt) {
    __shared__ u16 tile[32][33];
    int bh = blockIdx.z; int b = bh / 12, h = bh % 12;
    int t0 = blockIdx.x * 32, d0 = blockIdx.y * 32;
    int tx = threadIdx.x & 31, ty = threadIdx.x >> 5;
    #pragma unroll
    for (int i = 0; i < 32; i += 8) {
        int t = t0 + ty + i; int tc = min(t, 1295);
        tile[ty + i][tx] = qkv[(size_t)(b * 1296 + tc) * 2304 + 1536 + h * 64 + d0 + tx];
    }
    __syncthreads();
    #pragma unroll
    for (int i = 0; i < 32; i += 8) {
        int d = d0 + ty + i; int t = t0 + tx;
        if (t < 1296) vt[(size_t)(bh * 64 + d) * 1312 + t] = tile[tx][ty + i];
    }
}

// ---------------- GEMM: C[M][N] = A[M][K] @ Bt[N][K]^T (+epilogue) ----------------
// EPI: 0 = +bias, f32 store        (patch embed -> tok)
//      1 = bf16 store, no bias     (qkv)
//      2 = +bias, relu, bf16 store (mlp1 -> a1)
//      3 = +bias, +resid, f32 store(proj -> tok)
//      4 = +bias, +resid, f32 store TRANSPOSED to (B,E,T)   (mlp2 -> d_out)
template <int BN, int EPI>
__global__ __launch_bounds__(256) void gemm_k(const u16* __restrict__ A, const u16* __restrict__ Bt,
                                              const float* __restrict__ bias, const float* __restrict__ resid,
                                              void* __restrict__ Cout, int K, int ldc) {
    constexpr int M = 5184;
    constexpr int NF = BN / 32;
    __shared__ __align__(16) u16 lds[2][4096 + BN * 32];
    const int tid = threadIdx.x;
    const int l = tid & 63, w = tid >> 6;
    const int lr = l & 15, lq = l >> 4;
    const int wm = w >> 1, wn = w & 1;
    const int bm = blockIdx.y * 128;
    const int bn = blockIdx.x * BN;
    const int ar = l >> 2;   // row within 16-row chunk
    const int ap = l & 3;    // 16B piece slot

    f32x4 acc[4][NF];
    f32x4 zz = {0.f, 0.f, 0.f, 0.f};
    #pragma unroll
    for (int i = 0; i < 4; ++i)
        #pragma unroll
        for (int j = 0; j < NF; ++j) acc[i][j] = zz;

    const int nk = K >> 5;

    auto stage = [&](int buf, int kt) {
        #pragma unroll
        for (int i = 0; i < 2; ++i) {
            int c = 2 * w + i;
            int row = c * 16 + ar;
            int piece = ap ^ (row & 3);
            const u16* src = A + (size_t)min(bm + row, M - 1) * K + kt * 32 + piece * 8;
            gll16(src, &lds[buf][c * 512]);
        }
        if constexpr (BN == 128) {
            #pragma unroll
            for (int i = 0; i < 2; ++i) {
                int c = 2 * w + i;
                int row = c * 16 + ar;
                int piece = ap ^ (row & 3);
                const u16* src = Bt + (size_t)(bn + row) * K + kt * 32 + piece * 8;
                gll16(src, &lds[buf][4096 + c * 512]);
            }
        } else {
            int c = w;
            int row = c * 16 + ar;
            int piece = ap ^ (row & 3);
            const u16* src = Bt + (size_t)(bn + row) * K + kt * 32 + piece * 8;
            gll16(src, &lds[buf][4096 + c * 512]);
        }
    };

    stage(0, 0);
    __syncthreads();
    for (int kt = 0; kt < nk; ++kt) {
        int cur = kt & 1;
        if (kt + 1 < nk) stage(cur ^ 1, kt + 1);
        bf16x8 af[4], bfr[NF];
        #pragma unroll
        for (int mi = 0; mi < 4; ++mi) {
            int row = wm * 64 + mi * 16 + lr;
            af[mi] = *(const bf16x8*)&lds[cur][row * 32 + (lq ^ (row & 3)) * 8];
        }
        #pragma unroll
        for (int ni = 0; ni < NF; ++ni) {
            int row = wn * (BN / 2) + ni * 16 + lr;
            bfr[ni] = *(const bf16x8*)&lds[cur][4096 + row * 32 + (lq ^ (row & 3)) * 8];
        }
        #pragma unroll
        for (int mi = 0; mi < 4; ++mi)
            #pragma unroll
            for (int ni = 0; ni < NF; ++ni)
                acc[mi][ni] = __builtin_amdgcn_mfma_f32_16x16x32_bf16(af[mi], bfr[ni], acc[mi][ni], 0, 0, 0);
        __syncthreads();
    }

    // epilogue: D element (row = 4*lq + r within 16-tile, col = lr)
    #pragma unroll
    for (int mi = 0; mi < 4; ++mi) {
        #pragma unroll
        for (int ni = 0; ni < NF; ++ni) {
            int col = bn + wn * (BN / 2) + ni * 16 + lr;
            float bv = 0.f;
            if constexpr (EPI != 1) bv = bias[col];
            #pragma unroll
            for (int r = 0; r < 4; ++r) {
                int m = bm + wm * 64 + mi * 16 + 4 * lq + r;
                if (m < M) {
                    float v = acc[mi][ni][r] + bv;
                    if constexpr (EPI == 2) v = fmaxf(v, 0.f);
                    if constexpr (EPI == 3 || EPI == 4) v += resid[(size_t)m * ldc + col];
                    if constexpr (EPI == 0 || EPI == 3) {
                        ((float*)Cout)[(size_t)m * ldc + col] = v;
                    } else if constexpr (EPI == 4) {
                        int b = m / 1296, t = m - b * 1296;
                        ((float*)Cout)[(size_t)(b * 768 + col) * 1296 + t] = v;
                    } else {
                        ((u16*)Cout)[(size_t)m * ldc + col] = f2bf(v);
                    }
                }
            }
        }
    }
}

// ---------------- flash attention: causal, scale = 768^-0.5 ----------------
// qkv: bf16 [5184][2304] (q|k|v), vt: bf16 [48][64][1312], ao: bf16 [5184][768]
__global__ __launch_bounds__(256) void attn_k(const u16* __restrict__ qkv, const u16* __restrict__ vt,
                                              u16* __restrict__ ao) {
    const float SCALE = 0.03608439182435161f;   // 768^-0.5
    __shared__ __align__(16) u16 plds[4][16 * 40];
    const int wid = threadIdx.x >> 6, l = threadIdx.x & 63;
    const int bh = blockIdx.y, b = bh / 12, h = bh % 12;
    const int q0 = blockIdx.x * 64 + wid * 16;
    if (q0 >= 1296) return;
    const int lr = l & 15, lq = l >> 4;

    // Q fragments (A): row = q0+lr, k = d
    const u16* qp = qkv + (size_t)(b * 1296 + q0 + lr) * 2304 + h * 64;
    bf16x8 qa0 = *(const bf16x8*)(qp + 8 * lq);
    bf16x8 qa1 = *(const bf16x8*)(qp + 32 + 8 * lq);

    const u16* kbase = qkv + (size_t)(b * 1296) * 2304 + 768 + h * 64;
    const u16* vbase = vt + (size_t)bh * 64 * 1312;
    u16* pl = &plds[wid][0];

    f32x4 o[4];
    f32x4 zz = {0.f, 0.f, 0.f, 0.f};
    #pragma unroll
    for (int i = 0; i < 4; ++i) o[i] = zz;
    float mrow[4] = {-__builtin_inff(), -__builtin_inff(), -__builtin_inff(), -__builtin_inff()};
    float lsum[4] = {0.f, 0.f, 0.f, 0.f};

    const int nkt = ((q0 + 15) >> 5) + 1;
    for (int kt = 0; kt < nkt; ++kt) {
        const int k0 = kt * 32;
        f32x4 s[2];
        #pragma unroll
        for (int nt = 0; nt < 2; ++nt) {
            int tc = min(k0 + nt * 16 + lr, 1295);
            const u16* kp = kbase + (size_t)tc * 2304;
            bf16x8 kb0 = *(const bf16x8*)(kp + 8 * lq);
            bf16x8 kb1 = *(const bf16x8*)(kp + 32 + 8 * lq);
            f32x4 a = zz;
            a = __builtin_amdgcn_mfma_f32_16x16x32_bf16(qa0, kb0, a, 0, 0, 0);
            a = __builtin_amdgcn_mfma_f32_16x16x32_bf16(qa1, kb1, a, 0, 0, 0);
            s[nt] = a;
        }
        float tmax[4];
        #pragma unroll
        for (int r = 0; r < 4; ++r) {
            int qrow = q0 + 4 * lq + r;
            #pragma unroll
            for (int nt = 0; nt < 2; ++nt) {
                int tcol = k0 + nt * 16 + lr;
                float val = s[nt][r] * SCALE;
                s[nt][r] = (tcol <= qrow) ? val : -__builtin_inff();
            }
            tmax[r] = fmaxf(s[0][r], s[1][r]);
        }
        #pragma unroll
        for (int off = 1; off < 16; off <<= 1)
            #pragma unroll
            for (int r = 0; r < 4; ++r) tmax[r] = fmaxf(tmax[r], __shfl_xor(tmax[r], off));
        float alpha[4], tsum[4];
        #pragma unroll
        for (int r = 0; r < 4; ++r) {
            float nm = fmaxf(mrow[r], tmax[r]);
            alpha[r] = __expf(mrow[r] - nm);
            mrow[r] = nm;
            float accp = 0.f;
            #pragma unroll
            for (int nt = 0; nt < 2; ++nt) {
                float p = __expf(s[nt][r] - nm);
                s[nt][r] = p;
                accp += p;
            }
            tsum[r] = accp;
        }
        #pragma unroll
        for (int off = 1; off < 16; off <<= 1)
            #pragma unroll
            for (int r = 0; r < 4; ++r) tsum[r] += __shfl_xor(tsum[r], off);
        #pragma unroll
        for (int r = 0; r < 4; ++r) lsum[r] = lsum[r] * alpha[r] + tsum[r];
        #pragma unroll
        for (int dt = 0; dt < 4; ++dt)
            #pragma unroll
            for (int r = 0; r < 4; ++r) o[dt][r] *= alpha[r];
        // P: D-layout -> LDS [16 q][40 pad] -> A-layout
        #pragma unroll
        for (int nt = 0; nt < 2; ++nt)
            #pragma unroll
            for (int r = 0; r < 4; ++r)
                pl[(4 * lq + r) * 40 + nt * 16 + lr] = f2bf(s[nt][r]);
        __builtin_amdgcn_wave_barrier();
        bf16x8 pa = *(const bf16x8*)&pl[lr * 40 + 8 * lq];
        #pragma unroll
        for (int dt = 0; dt < 4; ++dt) {
            const u16* vp = vbase + (size_t)(dt * 16 + lr) * 1312 + k0 + 8 * lq;
            bf16x8 vb = *(const bf16x8*)vp;
            o[dt] = __builtin_amdgcn_mfma_f32_16x16x32_bf16(pa, vb, o[dt], 0, 0, 0);
        }
    }
    #pragma unroll
    for (int dt = 0; dt < 4; ++dt)
        #pragma unroll
        for (int r = 0; r < 4; ++r) {
            int qrow = q0 + 4 * lq + r;
            ao[(size_t)(b * 1296 + qrow) * 768 + h * 64 + dt * 16 + lr] = f2bf(o[dt][r] / lsum[r]);
        }
}

extern "C" void kernel_launch(void* const* d_in, const int* in_sizes, int n_in,
                              void* d_out, int out_size, void* d_ws, size_t ws_size,
                              hipStream_t stream) {
    const float* x      = (const float*)d_in[0];
    const float* conv_w = (const float*)d_in[1];
    const float* conv_b = (const float*)d_in[2];
    const float* wq     = (const float*)d_in[3];
    const float* wk     = (const float*)d_in[4];
    const float* wv     = (const float*)d_in[5];
    const float* wo     = (const float*)d_in[6];
    const float* bo     = (const float*)d_in[7];
    const float* w1     = (const float*)d_in[8];
    const float* b1     = (const float*)d_in[9];
    const float* w2     = (const float*)d_in[10];
    const float* b2     = (const float*)d_in[11];
    const float* ln1g   = (const float*)d_in[12];
    const float* ln1b   = (const float*)d_in[13];
    const float* ln2g   = (const float*)d_in[14];
    const float* ln2b   = (const float*)d_in[15];

    char* ws = (char*)d_ws;
    size_t off = 0;
    auto alloc = [&](size_t bytes) { char* p = ws + off; off = (off + bytes + 255) & ~(size_t)255; return p; };
    u16*   convw_bf = (u16*)alloc((size_t)768 * 768 * 2);
    u16*   wqkv_t   = (u16*)alloc((size_t)2304 * 768 * 2);
    u16*   wo_t     = (u16*)alloc((size_t)768 * 768 * 2);
    u16*   w1_t     = (u16*)alloc((size_t)3072 * 768 * 2);
    u16*   w2_t     = (u16*)alloc((size_t)768 * 3072 * 2);
    float* tok      = (float*)alloc((size_t)5184 * 768 * 4);
    u16*   hbuf     = (u16*)alloc((size_t)5184 * 768 * 2);
    u16*   apao     = (u16*)alloc((size_t)5184 * 768 * 2);   // patches, later attention output
    size_t qkv_bytes = ((size_t)5184 * 2304 * 2 + 255) & ~(size_t)255;
    size_t vt_bytes  = (size_t)48 * 64 * 1312 * 2;
    size_t a1_bytes  = (size_t)5184 * 3072 * 2;
    size_t big_bytes = qkv_bytes + vt_bytes;
    if (a1_bytes > big_bytes) big_bytes = a1_bytes;
    char* big = alloc(big_bytes);
    u16* qkvb = (u16*)big;
    u16* vtb  = (u16*)(big + qkv_bytes);
    u16* a1   = (u16*)big;   // overlays qkv+vt (dead after attention)

    // 1. weight prep
    convcvt_k<<<576, 256, 0, stream>>>(conv_w, convw_bf);
    wtrans_k<<<dim3(24, 24), 256, 0, stream>>>(wq, wqkv_t, 768, 768);
    wtrans_k<<<dim3(24, 24), 256, 0, stream>>>(wk, wqkv_t + 768 * 768, 768, 768);
    wtrans_k<<<dim3(24, 24), 256, 0, stream>>>(wv, wqkv_t + 2 * 768 * 768, 768, 768);
    wtrans_k<<<dim3(24, 24), 256, 0, stream>>>(wo, wo_t, 768, 768);
    wtrans_k<<<dim3(96, 24), 256, 0, stream>>>(w1, w1_t, 768, 3072);
    wtrans_k<<<dim3(24, 96), 256, 0, stream>>>(w2, w2_t, 3072, 768);
    // 2. patch gather
    patch_k<<<972, 256, 0, stream>>>(x, apao);
    // 3. patch-embed GEMM -> tok (f32)
    gemm_k<64, 0><<<dim3(12, 41), 256, 0, stream>>>(apao, convw_bf, conv_b, nullptr, tok, 768, 768);
    // 4. LN1 -> h (bf16)
    ln_k<<<1296, 256, 0, stream>>>(tok, ln1g, ln1b, hbuf);
    // 5. fused QKV GEMM -> qkv (bf16)
    gemm_k<128, 1><<<dim3(18, 41), 256, 0, stream>>>(hbuf, wqkv_t, nullptr, nullptr, qkvb, 768, 2304);
    // 6. V transpose
    vtrans_k<<<dim3(41, 2, 48), 256, 0, stream>>>(qkvb, vtb);
    // 7. attention -> ao (bf16, reuses patch buffer)
    attn_k<<<dim3(21, 48), 256, 0, stream>>>(qkvb, vtb, apao);
    // 8. output proj + residual -> tok
    gemm_k<64, 3><<<dim3(12, 41), 256, 0, stream>>>(apao, wo_t, bo, tok, tok, 768, 768);
    // 9. LN2 -> h
    ln_k<<<1296, 256, 0, stream>>>(tok, ln2g, ln2b, hbuf);
    // 10. MLP1 (relu) -> a1 (bf16)
    gemm_k<128, 2><<<dim3(24, 41), 256, 0, stream>>>(hbuf, w1_t, b1, nullptr, a1, 768, 3072);
    // 11. MLP2 + residual, store transposed (B,E,36,36) -> d_out (f32)
    gemm_k<64, 4><<<dim3(12, 41), 256, 0, stream>>>(a1, w2_t, b2, tok, d_out, 3072, 768);
}

// Round 2
// 403.858 us; speedup vs baseline: 1.0313x; 1.0313x over previous
//
#include <hip/hip_runtime.h>

typedef unsigned short u16;
typedef unsigned int u32;
typedef unsigned long long u64;
typedef float f32x4 __attribute__((ext_vector_type(4)));
typedef __bf16 bf16x8 __attribute__((ext_vector_type(8)));
typedef u16 u16x8 __attribute__((ext_vector_type(8)));

#define DEV __device__ __forceinline__

// ---- constants for this problem ----
// B=4, T=1296 (36x36 patches), E=768, H=12, HD=64, M = B*T = 5184
// patch K = C_IN*P*P = 3*16*16 = 768

DEV u16 f2bf(float f) {
    union { float f; u32 u; } un; un.f = f;
    u32 u = un.u;
    return (u16)((u + 0x7fffu + ((u >> 16) & 1u)) >> 16);
}

DEV void gll16(const u16* src, u16* dst) {
    auto g = (const __attribute__((address_space(1))) u32*)(src);
    auto s = (__attribute__((address_space(3))) u32*)(dst);
    __builtin_amdgcn_global_load_lds(g, s, 16, 0, 0);
}

// ---------------- weight convert / transpose ----------------
__global__ void convcvt_k(const float* __restrict__ src, u16* __restrict__ dst) {
    int i = blockIdx.x * 256 + threadIdx.x;          // one float4 per thread
    f32x4 v = ((const f32x4*)src)[i];
    union { u16 q[4]; u64 ll; } un;
    #pragma unroll
    for (int j = 0; j < 4; ++j) un.q[j] = f2bf(v[j]);
    ((u64*)dst)[i] = un.ll;
}

// src: f32 [K][N] row-major; dst: bf16 [N][K]
__global__ void wtrans_k(const float* __restrict__ src, u16* __restrict__ dst, int K, int N) {
    __shared__ float tile[32][33];
    int n0 = blockIdx.x * 32, k0 = blockIdx.y * 32;
    int tx = threadIdx.x & 31, ty = threadIdx.x >> 5;   // 32 x 8
    #pragma unroll
    for (int i = 0; i < 32; i += 8)
        tile[ty + i][tx] = src[(size_t)(k0 + ty + i) * N + n0 + tx];
    __syncthreads();
    #pragma unroll
    for (int i = 0; i < 32; i += 8)
        dst[(size_t)(n0 + ty + i) * K + k0 + tx] = f2bf(tile[tx][ty + i]);
}

// ---------------- patch gather: x (B,3,576,576) -> A [5184][768] bf16 ----------------
__global__ void patch_k(const float* __restrict__ x, u16* __restrict__ out) {
    int idx = blockIdx.x * 256 + threadIdx.x;   // [b][c][i][p][j], j innermost
    int j = idx % 36; int r1 = idx / 36;
    int p = r1 % 16;  int r2 = r1 / 16;
    int i = r2 % 36;  int r3 = r2 / 36;
    int c = r3 % 3;   int b = r3 / 3;
    const f32x4* src = (const f32x4*)(x + (size_t)((b * 3 + c) * 576 + i * 16 + p) * 576 + j * 16);
    u16x8 lo, hi;
    #pragma unroll
    for (int k = 0; k < 2; ++k) {
        f32x4 v = src[k];
        #pragma unroll
        for (int e = 0; e < 4; ++e) lo[k * 4 + e] = f2bf(v[e]);
    }
    #pragma unroll
    for (int k = 0; k < 2; ++k) {
        f32x4 v = src[2 + k];
        #pragma unroll
        for (int e = 0; e < 4; ++e) hi[k * 4 + e] = f2bf(v[e]);
    }
    u16* dst = out + (size_t)(b * 1296 + i * 36 + j) * 768 + c * 256 + p * 16;
    *(u16x8*)dst = lo;
    *(u16x8*)(dst + 8) = hi;
}

// ---------------- LayerNorm: f32 [5184][768] -> bf16 [5184][768] ----------------
__global__ __launch_bounds__(256) void ln_k(const float* __restrict__ x, const float* __restrict__ g,
                                            const float* __restrict__ bta, u16* __restrict__ out) {
    int row = blockIdx.x * 4 + (threadIdx.x >> 6);
    int l = threadIdx.x & 63;
    const float* xr = x + (size_t)row * 768;
    float v[12]; float s = 0.f, s2 = 0.f;
    #pragma unroll
    for (int i = 0; i < 12; ++i) { v[i] = xr[l + 64 * i]; s += v[i]; s2 += v[i] * v[i]; }
    #pragma unroll
    for (int off = 32; off; off >>= 1) { s += __shfl_xor(s, off); s2 += __shfl_xor(s2, off); }
    float mu = s * (1.f / 768.f);
    float var = s2 * (1.f / 768.f) - mu * mu;
    float rs = rsqrtf(var + 1e-5f);
    u16* orow = out + (size_t)row * 768;
    #pragma unroll
    for (int i = 0; i < 12; ++i) {
        int c = l + 64 * i;
        orow[c] = f2bf((v[i] - mu) * rs * g[c] + bta[c]);
    }
}

// ---------------- V transpose: qkv[.][1536+h*64+d] -> vt[bh][d][t] (t padded to 1344) ----------------
__global__ void vtrans_k(const u16* __restrict__ qkv, u16* __restrict__ vt) {
    __shared__ u16 tile[32][33];
    int bh = blockIdx.z; int b = bh / 12, h = bh % 12;
    int t0 = blockIdx.x * 32, d0 = blockIdx.y * 32;
    int tx = threadIdx.x & 31, ty = threadIdx.x >> 5;
    #pragma unroll
    for (int i = 0; i < 32; i += 8) {
        int t = t0 + ty + i; int tc = min(t, 1295);
        tile[ty + i][tx] = qkv[(size_t)(b * 1296 + tc) * 2304 + 1536 + h * 64 + d0 + tx];
    }
    __syncthreads();
    #pragma unroll
    for (int i = 0; i < 32; i += 8) {
        int d = d0 + ty + i; int t = t0 + tx;
        if (t < 1296) vt[(size_t)(bh * 64 + d) * 1344 + t] = tile[tx][ty + i];
    }
}

// ---------------- GEMM: C[M][N] = A[M][K] @ Bt[N][K]^T (+epilogue) ----------------
// EPI: 0 = +bias, f32 store        (patch embed -> tok)
//      1 = bf16 store, no bias     (qkv)
//      2 = +bias, relu, bf16 store (mlp1 -> a1)
//      3 = +bias, +resid, f32 store(proj -> tok)
//      4 = +bias, +resid, f32 store TRANSPOSED to (B,E,T)   (mlp2 -> d_out)
template <int BN, int EPI>
__global__ __launch_bounds__(256) void gemm_k(const u16* __restrict__ A, const u16* __restrict__ Bt,
                                              const float* __restrict__ bias, const float* __restrict__ resid,
                                              void* __restrict__ Cout, int K, int ldc) {
    constexpr int M = 5184;
    constexpr int NF = BN / 32;
    __shared__ __align__(16) u16 lds[2][4096 + BN * 32];
    const int tid = threadIdx.x;
    const int l = tid & 63, w = tid >> 6;
    const int lr = l & 15, lq = l >> 4;
    const int wm = w >> 1, wn = w & 1;
    const int bm = blockIdx.y * 128;
    const int bn = blockIdx.x * BN;
    const int ar = l >> 2;   // row within 16-row chunk
    const int ap = l & 3;    // 16B piece slot

    f32x4 acc[4][NF];
    f32x4 zz = {0.f, 0.f, 0.f, 0.f};
    #pragma unroll
    for (int i = 0; i < 4; ++i)
        #pragma unroll
        for (int j = 0; j < NF; ++j) acc[i][j] = zz;

    const int nk = K >> 5;

    auto stage = [&](int buf, int kt) {
        #pragma unroll
        for (int i = 0; i < 2; ++i) {
            int c = 2 * w + i;
            int row = c * 16 + ar;
            int piece = ap ^ (row & 3);
            const u16* src = A + (size_t)min(bm + row, M - 1) * K + kt * 32 + piece * 8;
            gll16(src, &lds[buf][c * 512]);
        }
        if constexpr (BN == 128) {
            #pragma unroll
            for (int i = 0; i < 2; ++i) {
                int c = 2 * w + i;
                int row = c * 16 + ar;
                int piece = ap ^ (row & 3);
                const u16* src = Bt + (size_t)(bn + row) * K + kt * 32 + piece * 8;
                gll16(src, &lds[buf][4096 + c * 512]);
            }
        } else {
            int c = w;
            int row = c * 16 + ar;
            int piece = ap ^ (row & 3);
            const u16* src = Bt + (size_t)(bn + row) * K + kt * 32 + piece * 8;
            gll16(src, &lds[buf][4096 + c * 512]);
        }
    };

    stage(0, 0);
    __syncthreads();
    for (int kt = 0; kt < nk; ++kt) {
        int cur = kt & 1;
        if (kt + 1 < nk) stage(cur ^ 1, kt + 1);
        bf16x8 af[4], bfr[NF];
        #pragma unroll
        for (int mi = 0; mi < 4; ++mi) {
            int row = wm * 64 + mi * 16 + lr;
            af[mi] = *(const bf16x8*)&lds[cur][row * 32 + (lq ^ (row & 3)) * 8];
        }
        #pragma unroll
        for (int ni = 0; ni < NF; ++ni) {
            int row = wn * (BN / 2) + ni * 16 + lr;
            bfr[ni] = *(const bf16x8*)&lds[cur][4096 + row * 32 + (lq ^ (row & 3)) * 8];
        }
        #pragma unroll
        for (int mi = 0; mi < 4; ++mi)
            #pragma unroll
            for (int ni = 0; ni < NF; ++ni)
                acc[mi][ni] = __builtin_amdgcn_mfma_f32_16x16x32_bf16(af[mi], bfr[ni], acc[mi][ni], 0, 0, 0);
        __syncthreads();
    }

    // epilogue: D element (row = 4*lq + r within 16-tile, col = lr)
    #pragma unroll
    for (int mi = 0; mi < 4; ++mi) {
        #pragma unroll
        for (int ni = 0; ni < NF; ++ni) {
            int col = bn + wn * (BN / 2) + ni * 16 + lr;
            float bv = 0.f;
            if constexpr (EPI != 1) bv = bias[col];
            #pragma unroll
            for (int r = 0; r < 4; ++r) {
                int m = bm + wm * 64 + mi * 16 + 4 * lq + r;
                if (m < M) {
                    float v = acc[mi][ni][r] + bv;
                    if constexpr (EPI == 2) v = fmaxf(v, 0.f);
                    if constexpr (EPI == 3 || EPI == 4) v += resid[(size_t)m * ldc + col];
                    if constexpr (EPI == 0 || EPI == 3) {
                        ((float*)Cout)[(size_t)m * ldc + col] = v;
                    } else if constexpr (EPI == 4) {
                        int b = m / 1296, t = m - b * 1296;
                        ((float*)Cout)[(size_t)(b * 768 + col) * 1296 + t] = v;
                    } else {
                        ((u16*)Cout)[(size_t)m * ldc + col] = f2bf(v);
                    }
                }
            }
        }
    }
}

// ---------------- flash attention: causal, scale = 768^-0.5, work-balanced ----------------
// Wave-unit u in [0,40]: handles q-tiles q0S=16u and q0L=16*(80-u)  (u=40: only L).
// KVBLK=64 per visit; K/V fragments shared between the two tiles in the joint range.
// qkv: bf16 [5184][2304] (q|k|v), vt: bf16 [48][64][1344], ao: bf16 [5184][768]
__global__ __launch_bounds__(256, 2) void attn_k(const u16* __restrict__ qkv, const u16* __restrict__ vt,
                                                 u16* __restrict__ ao) {
    const float SCALE = 0.03608439182435161f;   // 768^-0.5
    __shared__ __align__(16) u16 plds[4][16 * 72];
    const int wid = threadIdx.x >> 6, l = threadIdx.x & 63;
    const int bh = blockIdx.y, b = bh / 12, h = bh % 12;
    const int u = blockIdx.x * 4 + wid;
    if (u > 40) return;
    const int lr = l & 15, lq = l >> 4;
    const int q0S = 16 * u, q0L = 16 * (80 - u);
    const bool hasS = (u < 40);
    const int nktS = hasS ? ((q0S + 15) >> 6) + 1 : 0;
    const int nktL = ((q0L + 15) >> 6) + 1;

    const u16* kbase = qkv + (size_t)(b * 1296) * 2304 + 768 + h * 64;
    const u16* vbase = vt + (size_t)bh * 64 * 1344;
    u16* pl = &plds[wid][0];

    // Q fragments (A): row = q0+lr, k = d
    const u16* qpS = qkv + (size_t)(b * 1296 + q0S + lr) * 2304 + h * 64;
    const u16* qpL = qkv + (size_t)(b * 1296 + q0L + lr) * 2304 + h * 64;
    bf16x8 qS0 = *(const bf16x8*)(qpS + 8 * lq);
    bf16x8 qS1 = *(const bf16x8*)(qpS + 32 + 8 * lq);
    bf16x8 qL0 = *(const bf16x8*)(qpL + 8 * lq);
    bf16x8 qL1 = *(const bf16x8*)(qpL + 32 + 8 * lq);

    f32x4 zz = {0.f, 0.f, 0.f, 0.f};
    f32x4 oS[4], oL[4];
    float mS[4], mL[4], lSs[4], lLs[4];
    #pragma unroll
    for (int i = 0; i < 4; ++i) {
        oS[i] = zz; oL[i] = zz;
        mS[i] = -__builtin_inff(); mL[i] = -__builtin_inff();
        lSs[i] = 0.f; lLs[i] = 0.f;
    }

    bf16x8 kb[4][2], vb[4][2];

    auto visit = [&](int q0, bf16x8 qa0, bf16x8 qa1, f32x4 (&o)[4],
                     float (&mrow)[4], float (&lsum)[4], int k0) {
        f32x4 s[4];
        #pragma unroll
        for (int nt = 0; nt < 4; ++nt) {
            f32x4 a = zz;
            a = __builtin_amdgcn_mfma_f32_16x16x32_bf16(qa0, kb[nt][0], a, 0, 0, 0);
            a = __builtin_amdgcn_mfma_f32_16x16x32_bf16(qa1, kb[nt][1], a, 0, 0, 0);
            s[nt] = a;
        }
        float tmax[4];
        #pragma unroll
        for (int r = 0; r < 4; ++r) {
            int qrow = q0 + 4 * lq + r;
            #pragma unroll
            for (int nt = 0; nt < 4; ++nt) {
                int tcol = k0 + nt * 16 + lr;
                float val = s[nt][r] * SCALE;
                s[nt][r] = (tcol <= qrow) ? val : -__builtin_inff();
            }
            tmax[r] = fmaxf(fmaxf(s[0][r], s[1][r]), fmaxf(s[2][r], s[3][r]));
        }
        #pragma unroll
        for (int off = 1; off < 16; off <<= 1)
            #pragma unroll
            for (int r = 0; r < 4; ++r) tmax[r] = fmaxf(tmax[r], __shfl_xor(tmax[r], off));
        float alpha[4], tsum[4];
        #pragma unroll
        for (int r = 0; r < 4; ++r) {
            float nm = fmaxf(mrow[r], tmax[r]);
            alpha[r] = __expf(mrow[r] - nm);
            mrow[r] = nm;
            float accp = 0.f;
            #pragma unroll
            for (int nt = 0; nt < 4; ++nt) {
                float p = __expf(s[nt][r] - nm);
                s[nt][r] = p;
                accp += p;
            }
            tsum[r] = accp;
        }
        #pragma unroll
        for (int off = 1; off < 16; off <<= 1)
            #pragma unroll
            for (int r = 0; r < 4; ++r) tsum[r] += __shfl_xor(tsum[r], off);
        #pragma unroll
        for (int r = 0; r < 4; ++r) lsum[r] = lsum[r] * alpha[r] + tsum[r];
        #pragma unroll
        for (int dt = 0; dt < 4; ++dt)
            #pragma unroll
            for (int r = 0; r < 4; ++r) o[dt][r] *= alpha[r];
        // P: D-layout -> LDS [16 q][72 pad] -> A-layout
        #pragma unroll
        for (int nt = 0; nt < 4; ++nt)
            #pragma unroll
            for (int r = 0; r < 4; ++r)
                pl[(4 * lq + r) * 72 + nt * 16 + lr] = f2bf(s[nt][r]);
        __builtin_amdgcn_wave_barrier();
        bf16x8 pa0 = *(const bf16x8*)&pl[lr * 72 + 8 * lq];
        bf16x8 pa1 = *(const bf16x8*)&pl[lr * 72 + 32 + 8 * lq];
        #pragma unroll
        for (int dt = 0; dt < 4; ++dt) {
            o[dt] = __builtin_amdgcn_mfma_f32_16x16x32_bf16(pa0, vb[dt][0], o[dt], 0, 0, 0);
            o[dt] = __builtin_amdgcn_mfma_f32_16x16x32_bf16(pa1, vb[dt][1], o[dt], 0, 0, 0);
        }
        __builtin_amdgcn_wave_barrier();  // protect P buffer before next overwrite
    };

    for (int kt = 0; kt < nktL; ++kt) {
        const int k0 = kt * 64;
        // shared K fragments (B operand): col = k, kdim = d
        #pragma unroll
        for (int nt = 0; nt < 4; ++nt) {
            int tc = min(k0 + nt * 16 + lr, 1295);
            const u16* kp = kbase + (size_t)tc * 2304;
            kb[nt][0] = *(const bf16x8*)(kp + 8 * lq);
            kb[nt][1] = *(const bf16x8*)(kp + 32 + 8 * lq);
        }
        // shared V fragments (B operand for PV): col = d, kdim = k
        #pragma unroll
        for (int dt = 0; dt < 4; ++dt) {
            const u16* vp = vbase + (size_t)(dt * 16 + lr) * 1344 + k0 + 8 * lq;
            vb[dt][0] = *(const bf16x8*)vp;
            vb[dt][1] = *(const bf16x8*)(vp + 32);
        }
        if (kt < nktS) visit(q0S, qS0, qS1, oS, mS, lSs, k0);
        visit(q0L, qL0, qL1, oL, mL, lLs, k0);
    }

    #pragma unroll
    for (int dt = 0; dt < 4; ++dt)
        #pragma unroll
        for (int r = 0; r < 4; ++r) {
            if (hasS) {
                int qrow = q0S + 4 * lq + r;
                ao[(size_t)(b * 1296 + qrow) * 768 + h * 64 + dt * 16 + lr] = f2bf(oS[dt][r] / lSs[r]);
            }
            int qrowL = q0L + 4 * lq + r;
            ao[(size_t)(b * 1296 + qrowL) * 768 + h * 64 + dt * 16 + lr] = f2bf(oL[dt][r] / lLs[r]);
        }
}

extern "C" void kernel_launch(void* const* d_in, const int* in_sizes, int n_in,
                              void* d_out, int out_size, void* d_ws, size_t ws_size,
                              hipStream_t stream) {
    const float* x      = (const float*)d_in[0];
    const float* conv_w = (const float*)d_in[1];
    const float* conv_b = (const float*)d_in[2];
    const float* wq     = (const float*)d_in[3];
    const float* wk     = (const float*)d_in[4];
    const float* wv     = (const float*)d_in[5];
    const float* wo     = (const float*)d_in[6];
    const float* bo     = (const float*)d_in[7];
    const float* w1     = (const float*)d_in[8];
    const float* b1     = (const float*)d_in[9];
    const float* w2     = (const float*)d_in[10];
    const float* b2     = (const float*)d_in[11];
    const float* ln1g   = (const float*)d_in[12];
    const float* ln1b   = (const float*)d_in[13];
    const float* ln2g   = (const float*)d_in[14];
    const float* ln2b   = (const float*)d_in[15];

    char* ws = (char*)d_ws;
    size_t off = 0;
    auto alloc = [&](size_t bytes) { char* p = ws + off; off = (off + bytes + 255) & ~(size_t)255; return p; };
    u16*   convw_bf = (u16*)alloc((size_t)768 * 768 * 2);
    u16*   wqkv_t   = (u16*)alloc((size_t)2304 * 768 * 2);
    u16*   wo_t     = (u16*)alloc((size_t)768 * 768 * 2);
    u16*   w1_t     = (u16*)alloc((size_t)3072 * 768 * 2);
    u16*   w2_t     = (u16*)alloc((size_t)768 * 3072 * 2);
    float* tok      = (float*)alloc((size_t)5184 * 768 * 4);
    u16*   hbuf     = (u16*)alloc((size_t)5184 * 768 * 2);
    u16*   apao     = (u16*)alloc((size_t)5184 * 768 * 2);   // patches, later attention output
    size_t qkv_bytes = ((size_t)5184 * 2304 * 2 + 255) & ~(size_t)255;
    size_t vt_bytes  = (size_t)48 * 64 * 1344 * 2;
    size_t a1_bytes  = (size_t)5184 * 3072 * 2;
    size_t big_bytes = qkv_bytes + vt_bytes;
    if (a1_bytes > big_bytes) big_bytes = a1_bytes;
    char* big = alloc(big_bytes);
    u16* qkvb = (u16*)big;
    u16* vtb  = (u16*)(big + qkv_bytes);
    u16* a1   = (u16*)big;   // overlays qkv+vt (dead after attention)

    // 1. weight prep
    convcvt_k<<<576, 256, 0, stream>>>(conv_w, convw_bf);
    wtrans_k<<<dim3(24, 24), 256, 0, stream>>>(wq, wqkv_t, 768, 768);
    wtrans_k<<<dim3(24, 24), 256, 0, stream>>>(wk, wqkv_t + 768 * 768, 768, 768);
    wtrans_k<<<dim3(24, 24), 256, 0, stream>>>(wv, wqkv_t + 2 * 768 * 768, 768, 768);
    wtrans_k<<<dim3(24, 24), 256, 0, stream>>>(wo, wo_t, 768, 768);
    wtrans_k<<<dim3(96, 24), 256, 0, stream>>>(w1, w1_t, 768, 3072);
    wtrans_k<<<dim3(24, 96), 256, 0, stream>>>(w2, w2_t, 3072, 768);
    // 2. patch gather
    patch_k<<<972, 256, 0, stream>>>(x, apao);
    // 3. patch-embed GEMM -> tok (f32)
    gemm_k<64, 0><<<dim3(12, 41), 256, 0, stream>>>(apao, convw_bf, conv_b, nullptr, tok, 768, 768);
    // 4. LN1 -> h (bf16)
    ln_k<<<1296, 256, 0, stream>>>(tok, ln1g, ln1b, hbuf);
    // 5. fused QKV GEMM -> qkv (bf16)
    gemm_k<128, 1><<<dim3(18, 41), 256, 0, stream>>>(hbuf, wqkv_t, nullptr, nullptr, qkvb, 768, 2304);
    // 6. V transpose
    vtrans_k<<<dim3(41, 2, 48), 256, 0, stream>>>(qkvb, vtb);
    // 7. attention -> ao (bf16, reuses patch buffer), work-balanced pairing
    attn_k<<<dim3(11, 48), 256, 0, stream>>>(qkvb, vtb, apao);
    // 8. output proj + residual -> tok
    gemm_k<64, 3><<<dim3(12, 41), 256, 0, stream>>>(apao, wo_t, bo, tok, tok, 768, 768);
    // 9. LN2 -> h
    ln_k<<<1296, 256, 0, stream>>>(tok, ln2g, ln2b, hbuf);
    // 10. MLP1 (relu) -> a1 (bf16)
    gemm_k<128, 2><<<dim3(24, 41), 256, 0, stream>>>(hbuf, w1_t, b1, nullptr, a1, 768, 3072);
    // 11. MLP2 + residual, store transposed (B,E,36,36) -> d_out (f32)
    gemm_k<64, 4><<<dim3(12, 41), 256, 0, stream>>>(a1, w2_t, b2, tok, d_out, 3072, 768);
}

// Round 4
// 383.564 us; speedup vs baseline: 1.0858x; 1.0529x over previous
//
#include <hip/hip_runtime.h>

typedef unsigned short u16;
typedef unsigned int u32;
typedef unsigned long long u64;
typedef float f32x4 __attribute__((ext_vector_type(4)));
typedef __bf16 bf16x8 __attribute__((ext_vector_type(8)));
typedef u16 u16x8 __attribute__((ext_vector_type(8)));

#define DEV __device__ __forceinline__

// ---- constants for this problem ----
// B=4, T=1296 (36x36 patches), E=768, H=12, HD=64, M = B*T = 5184
// patch K = C_IN*P*P = 3*16*16 = 768

DEV u16 f2bf(float f) {
    union { float f; u32 u; } un; un.f = f;
    u32 u = un.u;
    return (u16)((u + 0x7fffu + ((u >> 16) & 1u)) >> 16);
}

DEV void gll16(const u16* src, u16* dst) {
    auto g = (const __attribute__((address_space(1))) u32*)(src);
    auto s = (__attribute__((address_space(3))) u32*)(dst);
    __builtin_amdgcn_global_load_lds(g, s, 16, 0, 0);
}

// ---------------- weight convert / transpose ----------------
__global__ void convcvt_k(const float* __restrict__ src, u16* __restrict__ dst) {
    int i = blockIdx.x * 256 + threadIdx.x;          // one float4 per thread
    f32x4 v = ((const f32x4*)src)[i];
    union { u16 q[4]; u64 ll; } un;
    #pragma unroll
    for (int j = 0; j < 4; ++j) un.q[j] = f2bf(v[j]);
    ((u64*)dst)[i] = un.ll;
}

// src: f32 [K][N] row-major; dst: bf16 [N][K]
__global__ void wtrans_k(const float* __restrict__ src, u16* __restrict__ dst, int K, int N) {
    __shared__ float tile[32][33];
    int n0 = blockIdx.x * 32, k0 = blockIdx.y * 32;
    int tx = threadIdx.x & 31, ty = threadIdx.x >> 5;   // 32 x 8
    #pragma unroll
    for (int i = 0; i < 32; i += 8)
        tile[ty + i][tx] = src[(size_t)(k0 + ty + i) * N + n0 + tx];
    __syncthreads();
    #pragma unroll
    for (int i = 0; i < 32; i += 8)
        dst[(size_t)(n0 + ty + i) * K + k0 + tx] = f2bf(tile[tx][ty + i]);
}

// ---------------- patch gather: x (B,3,576,576) -> A [5184][768] bf16 ----------------
__global__ void patch_k(const float* __restrict__ x, u16* __restrict__ out) {
    int idx = blockIdx.x * 256 + threadIdx.x;   // [b][c][i][p][j], j innermost
    int j = idx % 36; int r1 = idx / 36;
    int p = r1 % 16;  int r2 = r1 / 16;
    int i = r2 % 36;  int r3 = r2 / 36;
    int c = r3 % 3;   int b = r3 / 3;
    const f32x4* src = (const f32x4*)(x + (size_t)((b * 3 + c) * 576 + i * 16 + p) * 576 + j * 16);
    u16x8 lo, hi;
    #pragma unroll
    for (int k = 0; k < 2; ++k) {
        f32x4 v = src[k];
        #pragma unroll
        for (int e = 0; e < 4; ++e) lo[k * 4 + e] = f2bf(v[e]);
    }
    #pragma unroll
    for (int k = 0; k < 2; ++k) {
        f32x4 v = src[2 + k];
        #pragma unroll
        for (int e = 0; e < 4; ++e) hi[k * 4 + e] = f2bf(v[e]);
    }
    u16* dst = out + (size_t)(b * 1296 + i * 36 + j) * 768 + c * 256 + p * 16;
    *(u16x8*)dst = lo;
    *(u16x8*)(dst + 8) = hi;
}

// ---------------- LayerNorm: f32 [5184][768] -> bf16 [5184][768] ----------------
__global__ __launch_bounds__(256) void ln_k(const float* __restrict__ x, const float* __restrict__ g,
                                            const float* __restrict__ bta, u16* __restrict__ out) {
    int row = blockIdx.x * 4 + (threadIdx.x >> 6);
    int l = threadIdx.x & 63;
    const float* xr = x + (size_t)row * 768;
    float v[12]; float s = 0.f, s2 = 0.f;
    #pragma unroll
    for (int i = 0; i < 12; ++i) { v[i] = xr[l + 64 * i]; s += v[i]; s2 += v[i] * v[i]; }
    #pragma unroll
    for (int off = 32; off; off >>= 1) { s += __shfl_xor(s, off); s2 += __shfl_xor(s2, off); }
    float mu = s * (1.f / 768.f);
    float var = s2 * (1.f / 768.f) - mu * mu;
    float rs = rsqrtf(var + 1e-5f);
    u16* orow = out + (size_t)row * 768;
    #pragma unroll
    for (int i = 0; i < 12; ++i) {
        int c = l + 64 * i;
        orow[c] = f2bf((v[i] - mu) * rs * g[c] + bta[c]);
    }
}

// ---------------- V transpose: qkv[.][1536+h*64+d] -> vt[bh][d][t] (t padded to 1344) ----------------
__global__ void vtrans_k(const u16* __restrict__ qkv, u16* __restrict__ vt) {
    __shared__ u16 tile[32][33];
    int bh = blockIdx.z; int b = bh / 12, h = bh % 12;
    int t0 = blockIdx.x * 32, d0 = blockIdx.y * 32;
    int tx = threadIdx.x & 31, ty = threadIdx.x >> 5;
    #pragma unroll
    for (int i = 0; i < 32; i += 8) {
        int t = t0 + ty + i; int tc = min(t, 1295);
        tile[ty + i][tx] = qkv[(size_t)(b * 1296 + tc) * 2304 + 1536 + h * 64 + d0 + tx];
    }
    __syncthreads();
    #pragma unroll
    for (int i = 0; i < 32; i += 8) {
        int d = d0 + ty + i; int t = t0 + tx;
        if (t < 1296) vt[(size_t)(bh * 64 + d) * 1344 + t] = tile[tx][ty + i];
    }
}

// ---------------- GEMM: C[M][N] = A[M][K] @ Bt[N][K]^T (+epilogue) ----------------
// EPI: 0 = +bias, f32 store        (patch embed -> tok)
//      1 = bf16 store, no bias     (qkv)
//      2 = +bias, relu, bf16 store (mlp1 -> a1)
//      3 = +bias, +resid, f32 store(proj -> tok)
//      4 = +bias, +resid, f32 store TRANSPOSED to (B,E,T)   (mlp2 -> d_out)
template <int BN, int EPI>
__global__ __launch_bounds__(256) void gemm_k(const u16* __restrict__ A, const u16* __restrict__ Bt,
                                              const float* __restrict__ bias, const float* __restrict__ resid,
                                              void* __restrict__ Cout, int K, int ldc) {
    constexpr int M = 5184;
    constexpr int NF = BN / 32;
    __shared__ __align__(16) u16 lds[2][4096 + BN * 32];
    const int tid = threadIdx.x;
    const int l = tid & 63, w = tid >> 6;
    const int lr = l & 15, lq = l >> 4;
    const int wm = w >> 1, wn = w & 1;
    const int bm = blockIdx.y * 128;
    const int bn = blockIdx.x * BN;
    const int ar = l >> 2;   // row within 16-row chunk
    const int ap = l & 3;    // 16B piece slot

    f32x4 acc[4][NF];
    f32x4 zz = {0.f, 0.f, 0.f, 0.f};
    #pragma unroll
    for (int i = 0; i < 4; ++i)
        #pragma unroll
        for (int j = 0; j < NF; ++j) acc[i][j] = zz;

    const int nk = K >> 5;

    auto stage = [&](int buf, int kt) {
        #pragma unroll
        for (int i = 0; i < 2; ++i) {
            int c = 2 * w + i;
            int row = c * 16 + ar;
            int piece = ap ^ (row & 3);
            const u16* src = A + (size_t)min(bm + row, M - 1) * K + kt * 32 + piece * 8;
            gll16(src, &lds[buf][c * 512]);
        }
        if constexpr (BN == 128) {
            #pragma unroll
            for (int i = 0; i < 2; ++i) {
                int c = 2 * w + i;
                int row = c * 16 + ar;
                int piece = ap ^ (row & 3);
                const u16* src = Bt + (size_t)(bn + row) * K + kt * 32 + piece * 8;
                gll16(src, &lds[buf][4096 + c * 512]);
            }
        } else {
            int c = w;
            int row = c * 16 + ar;
            int piece = ap ^ (row & 3);
            const u16* src = Bt + (size_t)(bn + row) * K + kt * 32 + piece * 8;
            gll16(src, &lds[buf][4096 + c * 512]);
        }
    };

    stage(0, 0);
    __syncthreads();
    for (int kt = 0; kt < nk; ++kt) {
        int cur = kt & 1;
        if (kt + 1 < nk) stage(cur ^ 1, kt + 1);
        bf16x8 af[4], bfr[NF];
        #pragma unroll
        for (int mi = 0; mi < 4; ++mi) {
            int row = wm * 64 + mi * 16 + lr;
            af[mi] = *(const bf16x8*)&lds[cur][row * 32 + (lq ^ (row & 3)) * 8];
        }
        #pragma unroll
        for (int ni = 0; ni < NF; ++ni) {
            int row = wn * (BN / 2) + ni * 16 + lr;
            bfr[ni] = *(const bf16x8*)&lds[cur][4096 + row * 32 + (lq ^ (row & 3)) * 8];
        }
        #pragma unroll
        for (int mi = 0; mi < 4; ++mi)
            #pragma unroll
            for (int ni = 0; ni < NF; ++ni)
                acc[mi][ni] = __builtin_amdgcn_mfma_f32_16x16x32_bf16(af[mi], bfr[ni], acc[mi][ni], 0, 0, 0);
        __syncthreads();
    }

    // epilogue: D element (row = 4*lq + r within 16-tile, col = lr)
    #pragma unroll
    for (int mi = 0; mi < 4; ++mi) {
        #pragma unroll
        for (int ni = 0; ni < NF; ++ni) {
            int col = bn + wn * (BN / 2) + ni * 16 + lr;
            float bv = 0.f;
            if constexpr (EPI != 1) bv = bias[col];
            #pragma unroll
            for (int r = 0; r < 4; ++r) {
                int m = bm + wm * 64 + mi * 16 + 4 * lq + r;
                if (m < M) {
                    float v = acc[mi][ni][r] + bv;
                    if constexpr (EPI == 2) v = fmaxf(v, 0.f);
                    if constexpr (EPI == 3 || EPI == 4) v += resid[(size_t)m * ldc + col];
                    if constexpr (EPI == 0 || EPI == 3) {
                        ((float*)Cout)[(size_t)m * ldc + col] = v;
                    } else if constexpr (EPI == 4) {
                        int b = m / 1296, t = m - b * 1296;
                        ((float*)Cout)[(size_t)(b * 768 + col) * 1296 + t] = v;
                    } else {
                        ((u16*)Cout)[(size_t)m * ldc + col] = f2bf(v);
                    }
                }
            }
        }
    }
}

// ---------------- flash attention v3: causal, balanced pairing + LDS-staged K/V ----------------
// 1D grid of 528 blocks; decode keeps all 11 blocks of a bh on one XCD (id%8 == bh%8).
// Wave-unit u = bx*4+wid in [0,40]: q-tiles q0S=16u (u<40) and q0L=16*(80-u).
// Per k-visit (KVBLK=64): K-tile [64k][64d] and V-tile [64d][64k] cooperatively staged
// into double-buffered LDS via global_load_lds with XOR-swizzled source (rule #21).
__global__ __launch_bounds__(256, 2) void attn_k(const u16* __restrict__ qkv, const u16* __restrict__ vt,
                                                 u16* __restrict__ ao) {
    const float SCALE = 0.03608439182435161f;   // 768^-0.5
    __shared__ __align__(16) u16 kv[2][2][4096]; // [buf][K/V][64 rows x 64 cols]
    __shared__ __align__(16) u16 plds[4][16 * 72];
    const int tid = threadIdx.x;
    const int wid = tid >> 6, l = tid & 63;
    // XCD-affinity decode: id%8 = bh%8
    const int id = blockIdx.x;
    const int xr = id & 7, sl = id >> 3;
    const int g = sl / 11, bx = sl - g * 11;
    const int bh = g * 8 + xr;
    const int b = bh / 12, h = bh % 12;
    const int uu = bx * 4 + wid;
    const int u = min(uu, 40);
    const bool valid = (uu <= 40);
    const int lr = l & 15, lq = l >> 4;
    const int q0S = 16 * u, q0L = 16 * (80 - u);
    const bool hasS = valid && (u < 40);
    const int nktS = (u < 40) ? (((q0S + 15) >> 6) + 1) : 0;
    const int nktL = ((q0L + 15) >> 6) + 1;
    const int umin = min(bx * 4, 40);
    const int nktmax = ((16 * (80 - umin) + 15) >> 6) + 1;

    const u16* kbase = qkv + (size_t)(b * 1296) * 2304 + 768 + h * 64;
    const u16* vbase = vt + (size_t)bh * 64 * 1344;
    u16* pl = &plds[wid][0];

    // Q fragments (A): row = q0+lr, k = d
    const u16* qpS = qkv + (size_t)(b * 1296 + q0S + lr) * 2304 + h * 64;
    const u16* qpL = qkv + (size_t)(b * 1296 + q0L + lr) * 2304 + h * 64;
    bf16x8 qS0 = *(const bf16x8*)(qpS + 8 * lq);
    bf16x8 qS1 = *(const bf16x8*)(qpS + 32 + 8 * lq);
    bf16x8 qL0 = *(const bf16x8*)(qpL + 8 * lq);
    bf16x8 qL1 = *(const bf16x8*)(qpL + 32 + 8 * lq);

    f32x4 zz = {0.f, 0.f, 0.f, 0.f};
    f32x4 oS[4], oL[4];
    float mS[4], mL[4], lSs[4], lLs[4];
    #pragma unroll
    for (int i = 0; i < 4; ++i) {
        oS[i] = zz; oL[i] = zz;
        mS[i] = -__builtin_inff(); mL[i] = -__builtin_inff();
        lSs[i] = 0.f; lLs[i] = 0.f;
    }

    // cooperative stage of K+V tiles for k0 = kt*64 into buffer `buf`.
    // global_load_lds dest = wave-uniform base + lane*16B; 512 slots per tile, wave w
    // section i covers slots i*256 + w*64 .. +63.  Linear LDS slot (row,piece) receives
    // global piece piece^(row&7) (source-side swizzle); readers apply the same XOR.
    auto stage = [&](int buf, int kt) {
        const int k0 = kt * 64;
        #pragma unroll
        for (int i = 0; i < 2; ++i) {
            int slot = tid + i * 256;      // 0..511 : 16B slots
            int row = slot >> 3;           // k index 0..63
            int piece = slot & 7;
            int sp = piece ^ (row & 7);
            int tc = min(k0 + row, 1295);
            gll16(kbase + (size_t)tc * 2304 + sp * 8,
                  &kv[buf][0][((tid & 0xFFFFFFC0) + i * 256) * 8]);
        }
        #pragma unroll
        for (int i = 0; i < 2; ++i) {
            int slot = tid + i * 256;
            int row = slot >> 3;           // d index 0..63
            int piece = slot & 7;
            int sp = piece ^ (row & 7);
            gll16(vbase + (size_t)row * 1344 + k0 + sp * 8,
                  &kv[buf][1][((tid & 0xFFFFFFC0) + i * 256) * 8]);
        }
    };

    bf16x8 kb[4][2], vb[4][2];

    auto visit = [&](int q0, bf16x8 qa0, bf16x8 qa1, f32x4 (&o)[4],
                     float (&mrow)[4], float (&lsum)[4], int k0) {
        f32x4 s[4];
        #pragma unroll
        for (int nt = 0; nt < 4; ++nt) {
            f32x4 a = zz;
            a = __builtin_amdgcn_mfma_f32_16x16x32_bf16(qa0, kb[nt][0], a, 0, 0, 0);
            a = __builtin_amdgcn_mfma_f32_16x16x32_bf16(qa1, kb[nt][1], a, 0, 0, 0);
            s[nt] = a;
        }
        float tmax[4];
        #pragma unroll
        for (int r = 0; r < 4; ++r) {
            int qrow = q0 + 4 * lq + r;
            #pragma unroll
            for (int nt = 0; nt < 4; ++nt) {
                int tcol = k0 + nt * 16 + lr;
                float val = s[nt][r] * SCALE;
                s[nt][r] = (tcol <= qrow) ? val : -__builtin_inff();
            }
            tmax[r] = fmaxf(fmaxf(s[0][r], s[1][r]), fmaxf(s[2][r], s[3][r]));
        }
        #pragma unroll
        for (int off = 1; off < 16; off <<= 1)
            #pragma unroll
            for (int r = 0; r < 4; ++r) tmax[r] = fmaxf(tmax[r], __shfl_xor(tmax[r], off));
        float alpha[4], tsum[4];
        #pragma unroll
        for (int r = 0; r < 4; ++r) {
            float nm = fmaxf(mrow[r], tmax[r]);
            alpha[r] = __expf(mrow[r] - nm);
            mrow[r] = nm;
            float accp = 0.f;
            #pragma unroll
            for (int nt = 0; nt < 4; ++nt) {
                float p = __expf(s[nt][r] - nm);
                s[nt][r] = p;
                accp += p;
            }
            tsum[r] = accp;
        }
        #pragma unroll
        for (int off = 1; off < 16; off <<= 1)
            #pragma unroll
            for (int r = 0; r < 4; ++r) tsum[r] += __shfl_xor(tsum[r], off);
        #pragma unroll
        for (int r = 0; r < 4; ++r) lsum[r] = lsum[r] * alpha[r] + tsum[r];
        #pragma unroll
        for (int dt = 0; dt < 4; ++dt)
            #pragma unroll
            for (int r = 0; r < 4; ++r) o[dt][r] *= alpha[r];
        // P: D-layout -> LDS [16 q][72 pad] -> A-layout
        #pragma unroll
        for (int nt = 0; nt < 4; ++nt)
            #pragma unroll
            for (int r = 0; r < 4; ++r)
                pl[(4 * lq + r) * 72 + nt * 16 + lr] = f2bf(s[nt][r]);
        __builtin_amdgcn_wave_barrier();
        bf16x8 pa0 = *(const bf16x8*)&pl[lr * 72 + 8 * lq];
        bf16x8 pa1 = *(const bf16x8*)&pl[lr * 72 + 32 + 8 * lq];
        #pragma unroll
        for (int dt = 0; dt < 4; ++dt) {
            o[dt] = __builtin_amdgcn_mfma_f32_16x16x32_bf16(pa0, vb[dt][0], o[dt], 0, 0, 0);
            o[dt] = __builtin_amdgcn_mfma_f32_16x16x32_bf16(pa1, vb[dt][1], o[dt], 0, 0, 0);
        }
        __builtin_amdgcn_wave_barrier();  // protect P buffer before next overwrite
    };

    stage(0, 0);
    for (int kt = 0; kt < nktmax; ++kt) {
        const int cur = kt & 1;
        const int k0 = kt * 64;
        __syncthreads();                       // stage(cur) complete; prior reads of cur^1 done
        if (kt + 1 < nktmax) stage(cur ^ 1, kt + 1);
        // load K/V fragments from LDS (swizzled read)
        #pragma unroll
        for (int nt = 0; nt < 4; ++nt) {
            int krow = nt * 16 + lr;
            kb[nt][0] = *(const bf16x8*)&kv[cur][0][krow * 64 + ((lq ^ (krow & 7)) << 3)];
            kb[nt][1] = *(const bf16x8*)&kv[cur][0][krow * 64 + (((lq + 4) ^ (krow & 7)) << 3)];
        }
        #pragma unroll
        for (int dt = 0; dt < 4; ++dt) {
            int vrow = dt * 16 + lr;
            vb[dt][0] = *(const bf16x8*)&kv[cur][1][vrow * 64 + ((lq ^ (vrow & 7)) << 3)];
            vb[dt][1] = *(const bf16x8*)&kv[cur][1][vrow * 64 + (((lq + 4) ^ (vrow & 7)) << 3)];
        }
        if (valid && kt < nktS) visit(q0S, qS0, qS1, oS, mS, lSs, k0);
        if (valid && kt < nktL) visit(q0L, qL0, qL1, oL, mL, lLs, k0);
    }

    if (valid) {
        #pragma unroll
        for (int dt = 0; dt < 4; ++dt)
            #pragma unroll
            for (int r = 0; r < 4; ++r) {
                if (hasS) {
                    int qrow = q0S + 4 * lq + r;
                    ao[(size_t)(b * 1296 + qrow) * 768 + h * 64 + dt * 16 + lr] = f2bf(oS[dt][r] / lSs[r]);
                }
                int qrowL = q0L + 4 * lq + r;
                ao[(size_t)(b * 1296 + qrowL) * 768 + h * 64 + dt * 16 + lr] = f2bf(oL[dt][r] / lLs[r]);
            }
    }
}

extern "C" void kernel_launch(void* const* d_in, const int* in_sizes, int n_in,
                              void* d_out, int out_size, void* d_ws, size_t ws_size,
                              hipStream_t stream) {
    const float* x      = (const float*)d_in[0];
    const float* conv_w = (const float*)d_in[1];
    const float* conv_b = (const float*)d_in[2];
    const float* wq     = (const float*)d_in[3];
    const float* wk     = (const float*)d_in[4];
    const float* wv     = (const float*)d_in[5];
    const float* wo     = (const float*)d_in[6];
    const float* bo     = (const float*)d_in[7];
    const float* w1     = (const float*)d_in[8];
    const float* b1     = (const float*)d_in[9];
    const float* w2     = (const float*)d_in[10];
    const float* b2     = (const float*)d_in[11];
    const float* ln1g   = (const float*)d_in[12];
    const float* ln1b   = (const float*)d_in[13];
    const float* ln2g   = (const float*)d_in[14];
    const float* ln2b   = (const float*)d_in[15];

    char* ws = (char*)d_ws;
    size_t off = 0;
    auto alloc = [&](size_t bytes) { char* p = ws + off; off = (off + bytes + 255) & ~(size_t)255; return p; };
    u16*   convw_bf = (u16*)alloc((size_t)768 * 768 * 2);
    u16*   wqkv_t   = (u16*)alloc((size_t)2304 * 768 * 2);
    u16*   wo_t     = (u16*)alloc((size_t)768 * 768 * 2);
    u16*   w1_t     = (u16*)alloc((size_t)3072 * 768 * 2);
    u16*   w2_t     = (u16*)alloc((size_t)768 * 3072 * 2);
    float* tok      = (float*)alloc((size_t)5184 * 768 * 4);
    u16*   hbuf     = (u16*)alloc((size_t)5184 * 768 * 2);
    u16*   apao     = (u16*)alloc((size_t)5184 * 768 * 2);   // patches, later attention output
    size_t qkv_bytes = ((size_t)5184 * 2304 * 2 + 255) & ~(size_t)255;
    size_t vt_bytes  = (size_t)48 * 64 * 1344 * 2;
    size_t a1_bytes  = (size_t)5184 * 3072 * 2;
    size_t big_bytes = qkv_bytes + vt_bytes;
    if (a1_bytes > big_bytes) big_bytes = a1_bytes;
    char* big = alloc(big_bytes);
    u16* qkvb = (u16*)big;
    u16* vtb  = (u16*)(big + qkv_bytes);
    u16* a1   = (u16*)big;   // overlays qkv+vt (dead after attention)

    // 1. weight prep
    convcvt_k<<<576, 256, 0, stream>>>(conv_w, convw_bf);
    wtrans_k<<<dim3(24, 24), 256, 0, stream>>>(wq, wqkv_t, 768, 768);
    wtrans_k<<<dim3(24, 24), 256, 0, stream>>>(wk, wqkv_t + 768 * 768, 768, 768);
    wtrans_k<<<dim3(24, 24), 256, 0, stream>>>(wv, wqkv_t + 2 * 768 * 768, 768, 768);
    wtrans_k<<<dim3(24, 24), 256, 0, stream>>>(wo, wo_t, 768, 768);
    wtrans_k<<<dim3(96, 24), 256, 0, stream>>>(w1, w1_t, 768, 3072);
    wtrans_k<<<dim3(24, 96), 256, 0, stream>>>(w2, w2_t, 3072, 768);
    // 2. patch gather
    patch_k<<<972, 256, 0, stream>>>(x, apao);
    // 3. patch-embed GEMM -> tok (f32)
    gemm_k<64, 0><<<dim3(12, 41), 256, 0, stream>>>(apao, convw_bf, conv_b, nullptr, tok, 768, 768);
    // 4. LN1 -> h (bf16)
    ln_k<<<1296, 256, 0, stream>>>(tok, ln1g, ln1b, hbuf);
    // 5. fused QKV GEMM -> qkv (bf16)
    gemm_k<128, 1><<<dim3(18, 41), 256, 0, stream>>>(hbuf, wqkv_t, nullptr, nullptr, qkvb, 768, 2304);
    // 6. V transpose
    vtrans_k<<<dim3(41, 2, 48), 256, 0, stream>>>(qkvb, vtb);
    // 7. attention -> ao (bf16, reuses patch buffer): balanced + LDS-staged, XCD-affine
    attn_k<<<528, 256, 0, stream>>>(qkvb, vtb, apao);
    // 8. output proj + residual -> tok
    gemm_k<64, 3><<<dim3(12, 41), 256, 0, stream>>>(apao, wo_t, bo, tok, tok, 768, 768);
    // 9. LN2 -> h
    ln_k<<<1296, 256, 0, stream>>>(tok, ln2g, ln2b, hbuf);
    // 10. MLP1 (relu) -> a1 (bf16)
    gemm_k<128, 2><<<dim3(24, 41), 256, 0, stream>>>(hbuf, w1_t, b1, nullptr, a1, 768, 3072);
    // 11. MLP2 + residual, store transposed (B,E,36,36) -> d_out (f32)
    gemm_k<64, 4><<<dim3(12, 41), 256, 0, stream>>>(a1, w2_t, b2, tok, d_out, 3072, 768);
}

// Round 5
// 350.781 us; speedup vs baseline: 1.1873x; 1.0935x over previous
//
#include <hip/hip_runtime.h>

typedef unsigned short u16;
typedef unsigned int u32;
typedef unsigned long long u64;
typedef float f32x4 __attribute__((ext_vector_type(4)));
typedef __bf16 bf16x8 __attribute__((ext_vector_type(8)));
typedef u16 u16x8 __attribute__((ext_vector_type(8)));

#define DEV __device__ __forceinline__

// ---- constants for this problem ----
// B=4, T=1296 (36x36 patches), E=768, H=12, HD=64, M = B*T = 5184
// patch K = C_IN*P*P = 3*16*16 = 768

DEV u16 f2bf(float f) {
    union { float f; u32 u; } un; un.f = f;
    u32 u = un.u;
    return (u16)((u + 0x7fffu + ((u >> 16) & 1u)) >> 16);
}

DEV void gll16(const u16* src, u16* dst) {
    auto g = (const __attribute__((address_space(1))) u32*)(src);
    auto s = (__attribute__((address_space(3))) u32*)(dst);
    __builtin_amdgcn_global_load_lds(g, s, 16, 0, 0);
}

// ---------------- weight convert / transpose ----------------
__global__ void convcvt_k(const float* __restrict__ src, u16* __restrict__ dst) {
    int i = blockIdx.x * 256 + threadIdx.x;          // one float4 per thread
    f32x4 v = ((const f32x4*)src)[i];
    union { u16 q[4]; u64 ll; } un;
    #pragma unroll
    for (int j = 0; j < 4; ++j) un.q[j] = f2bf(v[j]);
    ((u64*)dst)[i] = un.ll;
}

// src: f32 [K][N] row-major; dst: bf16 [N][K]
__global__ void wtrans_k(const float* __restrict__ src, u16* __restrict__ dst, int K, int N) {
    __shared__ float tile[32][33];
    int n0 = blockIdx.x * 32, k0 = blockIdx.y * 32;
    int tx = threadIdx.x & 31, ty = threadIdx.x >> 5;   // 32 x 8
    #pragma unroll
    for (int i = 0; i < 32; i += 8)
        tile[ty + i][tx] = src[(size_t)(k0 + ty + i) * N + n0 + tx];
    __syncthreads();
    #pragma unroll
    for (int i = 0; i < 32; i += 8)
        dst[(size_t)(n0 + ty + i) * K + k0 + tx] = f2bf(tile[tx][ty + i]);
}

// ---------------- patch gather: x (B,3,576,576) -> A [5184][768] bf16 ----------------
__global__ void patch_k(const float* __restrict__ x, u16* __restrict__ out) {
    int idx = blockIdx.x * 256 + threadIdx.x;   // [b][c][i][p][j], j innermost
    int j = idx % 36; int r1 = idx / 36;
    int p = r1 % 16;  int r2 = r1 / 16;
    int i = r2 % 36;  int r3 = r2 / 36;
    int c = r3 % 3;   int b = r3 / 3;
    const f32x4* src = (const f32x4*)(x + (size_t)((b * 3 + c) * 576 + i * 16 + p) * 576 + j * 16);
    u16x8 lo, hi;
    #pragma unroll
    for (int k = 0; k < 2; ++k) {
        f32x4 v = src[k];
        #pragma unroll
        for (int e = 0; e < 4; ++e) lo[k * 4 + e] = f2bf(v[e]);
    }
    #pragma unroll
    for (int k = 0; k < 2; ++k) {
        f32x4 v = src[2 + k];
        #pragma unroll
        for (int e = 0; e < 4; ++e) hi[k * 4 + e] = f2bf(v[e]);
    }
    u16* dst = out + (size_t)(b * 1296 + i * 36 + j) * 768 + c * 256 + p * 16;
    *(u16x8*)dst = lo;
    *(u16x8*)(dst + 8) = hi;
}

// ---------------- LayerNorm: f32 [5184][768] -> bf16 [5184][768] ----------------
__global__ __launch_bounds__(256) void ln_k(const float* __restrict__ x, const float* __restrict__ g,
                                            const float* __restrict__ bta, u16* __restrict__ out) {
    int row = blockIdx.x * 4 + (threadIdx.x >> 6);
    int l = threadIdx.x & 63;
    const float* xr = x + (size_t)row * 768;
    float v[12]; float s = 0.f, s2 = 0.f;
    #pragma unroll
    for (int i = 0; i < 12; ++i) { v[i] = xr[l + 64 * i]; s += v[i]; s2 += v[i] * v[i]; }
    #pragma unroll
    for (int off = 32; off; off >>= 1) { s += __shfl_xor(s, off); s2 += __shfl_xor(s2, off); }
    float mu = s * (1.f / 768.f);
    float var = s2 * (1.f / 768.f) - mu * mu;
    float rs = rsqrtf(var + 1e-5f);
    u16* orow = out + (size_t)row * 768;
    #pragma unroll
    for (int i = 0; i < 12; ++i) {
        int c = l + 64 * i;
        orow[c] = f2bf((v[i] - mu) * rs * g[c] + bta[c]);
    }
}

// ---------------- V transpose: qkv[.][1536+h*64+d] -> vt[bh][d][t] (t padded to 1344) ----------------
__global__ void vtrans_k(const u16* __restrict__ qkv, u16* __restrict__ vt) {
    __shared__ u16 tile[32][33];
    int bh = blockIdx.z; int b = bh / 12, h = bh % 12;
    int t0 = blockIdx.x * 32, d0 = blockIdx.y * 32;
    int tx = threadIdx.x & 31, ty = threadIdx.x >> 5;
    #pragma unroll
    for (int i = 0; i < 32; i += 8) {
        int t = t0 + ty + i; int tc = min(t, 1295);
        tile[ty + i][tx] = qkv[(size_t)(b * 1296 + tc) * 2304 + 1536 + h * 64 + d0 + tx];
    }
    __syncthreads();
    #pragma unroll
    for (int i = 0; i < 32; i += 8) {
        int d = d0 + ty + i; int t = t0 + tx;
        if (t < 1296) vt[(size_t)(bh * 64 + d) * 1344 + t] = tile[tx][ty + i];
    }
}

// ---------------- GEMM v2: C[M][N] = A[M][K] @ Bt[N][K]^T (+epilogue) ----------------
// BK=64 (128B LDS rows, full 32-bank span), piece^(row&7) swizzle (2-way max conflicts),
// 1D grid with bijective XCD-chunked decode (col-block fastest within an XCD).
// EPI: 0 = +bias, f32 store        (patch embed -> tok)
//      1 = bf16 store, no bias     (qkv)
//      2 = +bias, relu, bf16 store (mlp1 -> a1)
//      3 = +bias, +resid, f32 store(proj -> tok)
//      4 = +bias, +resid, f32 store TRANSPOSED to (B,E,T)   (mlp2 -> d_out)
template <int BN, int EPI>
__global__ __launch_bounds__(256) void gemm_k(const u16* __restrict__ A, const u16* __restrict__ Bt,
                                              const float* __restrict__ bias, const float* __restrict__ resid,
                                              void* __restrict__ Cout, int K, int ldc, int nbx) {
    constexpr int M = 5184;
    constexpr int NF = BN / 32;
    // [buf][(128 A-rows + BN B-rows) x 64 u16 (128B)]
    __shared__ __align__(16) u16 lds[2][(128 + BN) * 64];
    const int tid = threadIdx.x;
    const int l = tid & 63, w = tid >> 6;
    const int lr = l & 15, lq = l >> 4;
    const int wm = w >> 1, wn = w & 1;

    // bijective XCD-chunked decode: ids on XCD x are {x, x+8, ...}; chunk start x*q+min(x,r)
    const int total = nbx * 41;
    const int q = total >> 3, r = total & 7;
    const int x = blockIdx.x & 7;
    const int j = blockIdx.x >> 3;
    const int wrk = x * q + min(x, r) + j;
    const int by = wrk / nbx, bx = wrk - by * nbx;
    const int bm = by * 128;
    const int bn = bx * BN;

    f32x4 acc[4][NF];
    f32x4 zz = {0.f, 0.f, 0.f, 0.f};
    #pragma unroll
    for (int i = 0; i < 4; ++i)
        #pragma unroll
        for (int jj = 0; jj < NF; ++jj) acc[i][jj] = zz;

    const int nk = K >> 6;

    // stage A (128x64) + B (BNx64) for k-chunk kt into buffer buf.
    // 16B slot s=(row,piece): LDS linear, global source piece = piece^(row&7).
    auto stage = [&](int buf, int kt) {
        u16* abase = &lds[buf][0];
        #pragma unroll
        for (int i = 0; i < 4; ++i) {
            int slot = tid + i * 256;
            int row = slot >> 3, piece = slot & 7;
            int sp = piece ^ (row & 7);
            const u16* src = A + (size_t)min(bm + row, M - 1) * K + kt * 64 + sp * 8;
            gll16(src, abase + ((tid & ~63) + i * 256) * 8);
        }
        u16* bbase = &lds[buf][128 * 64];
        #pragma unroll
        for (int i = 0; i < NF; ++i) {
            int slot = tid + i * 256;
            int row = slot >> 3, piece = slot & 7;
            int sp = piece ^ (row & 7);
            const u16* src = Bt + (size_t)(bn + row) * K + kt * 64 + sp * 8;
            gll16(src, bbase + ((tid & ~63) + i * 256) * 8);
        }
    };

    stage(0, 0);
    __syncthreads();
    for (int kt = 0; kt < nk; ++kt) {
        int cur = kt & 1;
        if (kt + 1 < nk) stage(cur ^ 1, kt + 1);
        bf16x8 af[4][2], bfr[NF][2];
        #pragma unroll
        for (int mi = 0; mi < 4; ++mi) {
            int row = wm * 64 + mi * 16 + lr;
            #pragma unroll
            for (int ks = 0; ks < 2; ++ks)
                af[mi][ks] = *(const bf16x8*)&lds[cur][row * 64 + (((lq + 4 * ks) ^ (row & 7)) << 3)];
        }
        #pragma unroll
        for (int ni = 0; ni < NF; ++ni) {
            int row = wn * (BN / 2) + ni * 16 + lr;
            #pragma unroll
            for (int ks = 0; ks < 2; ++ks)
                bfr[ni][ks] = *(const bf16x8*)&lds[cur][128 * 64 + row * 64 + (((lq + 4 * ks) ^ (row & 7)) << 3)];
        }
        #pragma unroll
        for (int mi = 0; mi < 4; ++mi)
            #pragma unroll
            for (int ni = 0; ni < NF; ++ni) {
                acc[mi][ni] = __builtin_amdgcn_mfma_f32_16x16x32_bf16(af[mi][0], bfr[ni][0], acc[mi][ni], 0, 0, 0);
                acc[mi][ni] = __builtin_amdgcn_mfma_f32_16x16x32_bf16(af[mi][1], bfr[ni][1], acc[mi][ni], 0, 0, 0);
            }
        __syncthreads();
    }

    // epilogue: D element (row = 4*lq + r within 16-tile, col = lr)
    #pragma unroll
    for (int mi = 0; mi < 4; ++mi) {
        #pragma unroll
        for (int ni = 0; ni < NF; ++ni) {
            int col = bn + wn * (BN / 2) + ni * 16 + lr;
            float bv = 0.f;
            if constexpr (EPI != 1) bv = bias[col];
            #pragma unroll
            for (int rr = 0; rr < 4; ++rr) {
                int m = bm + wm * 64 + mi * 16 + 4 * lq + rr;
                if (m < M) {
                    float v = acc[mi][ni][rr] + bv;
                    if constexpr (EPI == 2) v = fmaxf(v, 0.f);
                    if constexpr (EPI == 3 || EPI == 4) v += resid[(size_t)m * ldc + col];
                    if constexpr (EPI == 0 || EPI == 3) {
                        ((float*)Cout)[(size_t)m * ldc + col] = v;
                    } else if constexpr (EPI == 4) {
                        int b = m / 1296, t = m - b * 1296;
                        ((float*)Cout)[(size_t)(b * 768 + col) * 1296 + t] = v;
                    } else {
                        ((u16*)Cout)[(size_t)m * ldc + col] = f2bf(v);
                    }
                }
            }
        }
    }
}

// ---------------- flash attention v3: causal, balanced pairing + LDS-staged K/V ----------------
// 1D grid of 528 blocks; decode keeps all 11 blocks of a bh on one XCD (id%8 == bh%8).
// Wave-unit u = bx*4+wid in [0,40]: q-tiles q0S=16u (u<40) and q0L=16*(80-u).
// Per k-visit (KVBLK=64): K-tile [64k][64d] and V-tile [64d][64k] cooperatively staged
// into double-buffered LDS via global_load_lds with XOR-swizzled source (rule #21).
__global__ __launch_bounds__(256, 2) void attn_k(const u16* __restrict__ qkv, const u16* __restrict__ vt,
                                                 u16* __restrict__ ao) {
    const float SCALE = 0.03608439182435161f;   // 768^-0.5
    __shared__ __align__(16) u16 kv[2][2][4096]; // [buf][K/V][64 rows x 64 cols]
    __shared__ __align__(16) u16 plds[4][16 * 72];
    const int tid = threadIdx.x;
    const int wid = tid >> 6, l = tid & 63;
    // XCD-affinity decode: id%8 = bh%8
    const int id = blockIdx.x;
    const int xr = id & 7, sl = id >> 3;
    const int g = sl / 11, bx = sl - g * 11;
    const int bh = g * 8 + xr;
    const int b = bh / 12, h = bh % 12;
    const int uu = bx * 4 + wid;
    const int u = min(uu, 40);
    const bool valid = (uu <= 40);
    const int lr = l & 15, lq = l >> 4;
    const int q0S = 16 * u, q0L = 16 * (80 - u);
    const bool hasS = valid && (u < 40);
    const int nktS = (u < 40) ? (((q0S + 15) >> 6) + 1) : 0;
    const int nktL = ((q0L + 15) >> 6) + 1;
    const int umin = min(bx * 4, 40);
    const int nktmax = ((16 * (80 - umin) + 15) >> 6) + 1;

    const u16* kbase = qkv + (size_t)(b * 1296) * 2304 + 768 + h * 64;
    const u16* vbase = vt + (size_t)bh * 64 * 1344;
    u16* pl = &plds[wid][0];

    // Q fragments (A): row = q0+lr, k = d
    const u16* qpS = qkv + (size_t)(b * 1296 + q0S + lr) * 2304 + h * 64;
    const u16* qpL = qkv + (size_t)(b * 1296 + q0L + lr) * 2304 + h * 64;
    bf16x8 qS0 = *(const bf16x8*)(qpS + 8 * lq);
    bf16x8 qS1 = *(const bf16x8*)(qpS + 32 + 8 * lq);
    bf16x8 qL0 = *(const bf16x8*)(qpL + 8 * lq);
    bf16x8 qL1 = *(const bf16x8*)(qpL + 32 + 8 * lq);

    f32x4 zz = {0.f, 0.f, 0.f, 0.f};
    f32x4 oS[4], oL[4];
    float mS[4], mL[4], lSs[4], lLs[4];
    #pragma unroll
    for (int i = 0; i < 4; ++i) {
        oS[i] = zz; oL[i] = zz;
        mS[i] = -__builtin_inff(); mL[i] = -__builtin_inff();
        lSs[i] = 0.f; lLs[i] = 0.f;
    }

    // cooperative stage of K+V tiles for k0 = kt*64 into buffer `buf`.
    // global_load_lds dest = wave-uniform base + lane*16B; 512 slots per tile, wave w
    // section i covers slots i*256 + w*64 .. +63.  Linear LDS slot (row,piece) receives
    // global piece piece^(row&7) (source-side swizzle); readers apply the same XOR.
    auto stage = [&](int buf, int kt) {
        const int k0 = kt * 64;
        #pragma unroll
        for (int i = 0; i < 2; ++i) {
            int slot = tid + i * 256;      // 0..511 : 16B slots
            int row = slot >> 3;           // k index 0..63
            int piece = slot & 7;
            int sp = piece ^ (row & 7);
            int tc = min(k0 + row, 1295);
            gll16(kbase + (size_t)tc * 2304 + sp * 8,
                  &kv[buf][0][((tid & 0xFFFFFFC0) + i * 256) * 8]);
        }
        #pragma unroll
        for (int i = 0; i < 2; ++i) {
            int slot = tid + i * 256;
            int row = slot >> 3;           // d index 0..63
            int piece = slot & 7;
            int sp = piece ^ (row & 7);
            gll16(vbase + (size_t)row * 1344 + k0 + sp * 8,
                  &kv[buf][1][((tid & 0xFFFFFFC0) + i * 256) * 8]);
        }
    };

    bf16x8 kb[4][2], vb[4][2];

    auto visit = [&](int q0, bf16x8 qa0, bf16x8 qa1, f32x4 (&o)[4],
                     float (&mrow)[4], float (&lsum)[4], int k0) {
        f32x4 s[4];
        #pragma unroll
        for (int nt = 0; nt < 4; ++nt) {
            f32x4 a = zz;
            a = __builtin_amdgcn_mfma_f32_16x16x32_bf16(qa0, kb[nt][0], a, 0, 0, 0);
            a = __builtin_amdgcn_mfma_f32_16x16x32_bf16(qa1, kb[nt][1], a, 0, 0, 0);
            s[nt] = a;
        }
        float tmax[4];
        #pragma unroll
        for (int r = 0; r < 4; ++r) {
            int qrow = q0 + 4 * lq + r;
            #pragma unroll
            for (int nt = 0; nt < 4; ++nt) {
                int tcol = k0 + nt * 16 + lr;
                float val = s[nt][r] * SCALE;
                s[nt][r] = (tcol <= qrow) ? val : -__builtin_inff();
            }
            tmax[r] = fmaxf(fmaxf(s[0][r], s[1][r]), fmaxf(s[2][r], s[3][r]));
        }
        #pragma unroll
        for (int off = 1; off < 16; off <<= 1)
            #pragma unroll
            for (int r = 0; r < 4; ++r) tmax[r] = fmaxf(tmax[r], __shfl_xor(tmax[r], off));
        float alpha[4], tsum[4];
        #pragma unroll
        for (int r = 0; r < 4; ++r) {
            float nm = fmaxf(mrow[r], tmax[r]);
            alpha[r] = __expf(mrow[r] - nm);
            mrow[r] = nm;
            float accp = 0.f;
            #pragma unroll
            for (int nt = 0; nt < 4; ++nt) {
                float p = __expf(s[nt][r] - nm);
                s[nt][r] = p;
                accp += p;
            }
            tsum[r] = accp;
        }
        #pragma unroll
        for (int off = 1; off < 16; off <<= 1)
            #pragma unroll
            for (int r = 0; r < 4; ++r) tsum[r] += __shfl_xor(tsum[r], off);
        #pragma unroll
        for (int r = 0; r < 4; ++r) lsum[r] = lsum[r] * alpha[r] + tsum[r];
        #pragma unroll
        for (int dt = 0; dt < 4; ++dt)
            #pragma unroll
            for (int r = 0; r < 4; ++r) o[dt][r] *= alpha[r];
        // P: D-layout -> LDS [16 q][72 pad] -> A-layout
        #pragma unroll
        for (int nt = 0; nt < 4; ++nt)
            #pragma unroll
            for (int r = 0; r < 4; ++r)
                pl[(4 * lq + r) * 72 + nt * 16 + lr] = f2bf(s[nt][r]);
        __builtin_amdgcn_wave_barrier();
        bf16x8 pa0 = *(const bf16x8*)&pl[lr * 72 + 8 * lq];
        bf16x8 pa1 = *(const bf16x8*)&pl[lr * 72 + 32 + 8 * lq];
        #pragma unroll
        for (int dt = 0; dt < 4; ++dt) {
            o[dt] = __builtin_amdgcn_mfma_f32_16x16x32_bf16(pa0, vb[dt][0], o[dt], 0, 0, 0);
            o[dt] = __builtin_amdgcn_mfma_f32_16x16x32_bf16(pa1, vb[dt][1], o[dt], 0, 0, 0);
        }
        __builtin_amdgcn_wave_barrier();  // protect P buffer before next overwrite
    };

    stage(0, 0);
    for (int kt = 0; kt < nktmax; ++kt) {
        const int cur = kt & 1;
        const int k0 = kt * 64;
        __syncthreads();                       // stage(cur) complete; prior reads of cur^1 done
        if (kt + 1 < nktmax) stage(cur ^ 1, kt + 1);
        // load K/V fragments from LDS (swizzled read)
        #pragma unroll
        for (int nt = 0; nt < 4; ++nt) {
            int krow = nt * 16 + lr;
            kb[nt][0] = *(const bf16x8*)&kv[cur][0][krow * 64 + ((lq ^ (krow & 7)) << 3)];
            kb[nt][1] = *(const bf16x8*)&kv[cur][0][krow * 64 + (((lq + 4) ^ (krow & 7)) << 3)];
        }
        #pragma unroll
        for (int dt = 0; dt < 4; ++dt) {
            int vrow = dt * 16 + lr;
            vb[dt][0] = *(const bf16x8*)&kv[cur][1][vrow * 64 + ((lq ^ (vrow & 7)) << 3)];
            vb[dt][1] = *(const bf16x8*)&kv[cur][1][vrow * 64 + (((lq + 4) ^ (vrow & 7)) << 3)];
        }
        if (valid && kt < nktS) visit(q0S, qS0, qS1, oS, mS, lSs, k0);
        if (valid && kt < nktL) visit(q0L, qL0, qL1, oL, mL, lLs, k0);
    }

    if (valid) {
        #pragma unroll
        for (int dt = 0; dt < 4; ++dt)
            #pragma unroll
            for (int r = 0; r < 4; ++r) {
                if (hasS) {
                    int qrow = q0S + 4 * lq + r;
                    ao[(size_t)(b * 1296 + qrow) * 768 + h * 64 + dt * 16 + lr] = f2bf(oS[dt][r] / lSs[r]);
                }
                int qrowL = q0L + 4 * lq + r;
                ao[(size_t)(b * 1296 + qrowL) * 768 + h * 64 + dt * 16 + lr] = f2bf(oL[dt][r] / lLs[r]);
            }
    }
}

extern "C" void kernel_launch(void* const* d_in, const int* in_sizes, int n_in,
                              void* d_out, int out_size, void* d_ws, size_t ws_size,
                              hipStream_t stream) {
    const float* x      = (const float*)d_in[0];
    const float* conv_w = (const float*)d_in[1];
    const float* conv_b = (const float*)d_in[2];
    const float* wq     = (const float*)d_in[3];
    const float* wk     = (const float*)d_in[4];
    const float* wv     = (const float*)d_in[5];
    const float* wo     = (const float*)d_in[6];
    const float* bo     = (const float*)d_in[7];
    const float* w1     = (const float*)d_in[8];
    const float* b1     = (const float*)d_in[9];
    const float* w2     = (const float*)d_in[10];
    const float* b2     = (const float*)d_in[11];
    const float* ln1g   = (const float*)d_in[12];
    const float* ln1b   = (const float*)d_in[13];
    const float* ln2g   = (const float*)d_in[14];
    const float* ln2b   = (const float*)d_in[15];

    char* ws = (char*)d_ws;
    size_t off = 0;
    auto alloc = [&](size_t bytes) { char* p = ws + off; off = (off + bytes + 255) & ~(size_t)255; return p; };
    u16*   convw_bf = (u16*)alloc((size_t)768 * 768 * 2);
    u16*   wqkv_t   = (u16*)alloc((size_t)2304 * 768 * 2);
    u16*   wo_t     = (u16*)alloc((size_t)768 * 768 * 2);
    u16*   w1_t     = (u16*)alloc((size_t)3072 * 768 * 2);
    u16*   w2_t     = (u16*)alloc((size_t)768 * 3072 * 2);
    float* tok      = (float*)alloc((size_t)5184 * 768 * 4);
    u16*   hbuf     = (u16*)alloc((size_t)5184 * 768 * 2);
    u16*   apao     = (u16*)alloc((size_t)5184 * 768 * 2);   // patches, later attention output
    size_t qkv_bytes = ((size_t)5184 * 2304 * 2 + 255) & ~(size_t)255;
    size_t vt_bytes  = (size_t)48 * 64 * 1344 * 2;
    size_t a1_bytes  = (size_t)5184 * 3072 * 2;
    size_t big_bytes = qkv_bytes + vt_bytes;
    if (a1_bytes > big_bytes) big_bytes = a1_bytes;
    char* big = alloc(big_bytes);
    u16* qkvb = (u16*)big;
    u16* vtb  = (u16*)(big + qkv_bytes);
    u16* a1   = (u16*)big;   // overlays qkv+vt (dead after attention)

    // 1. weight prep
    convcvt_k<<<576, 256, 0, stream>>>(conv_w, convw_bf);
    wtrans_k<<<dim3(24, 24), 256, 0, stream>>>(wq, wqkv_t, 768, 768);
    wtrans_k<<<dim3(24, 24), 256, 0, stream>>>(wk, wqkv_t + 768 * 768, 768, 768);
    wtrans_k<<<dim3(24, 24), 256, 0, stream>>>(wv, wqkv_t + 2 * 768 * 768, 768, 768);
    wtrans_k<<<dim3(24, 24), 256, 0, stream>>>(wo, wo_t, 768, 768);
    wtrans_k<<<dim3(96, 24), 256, 0, stream>>>(w1, w1_t, 768, 3072);
    wtrans_k<<<dim3(24, 96), 256, 0, stream>>>(w2, w2_t, 3072, 768);
    // 2. patch gather
    patch_k<<<972, 256, 0, stream>>>(x, apao);
    // 3. patch-embed GEMM -> tok (f32)
    gemm_k<64, 0><<<12 * 41, 256, 0, stream>>>(apao, convw_bf, conv_b, nullptr, tok, 768, 768, 12);
    // 4. LN1 -> h (bf16)
    ln_k<<<1296, 256, 0, stream>>>(tok, ln1g, ln1b, hbuf);
    // 5. fused QKV GEMM -> qkv (bf16)
    gemm_k<128, 1><<<18 * 41, 256, 0, stream>>>(hbuf, wqkv_t, nullptr, nullptr, qkvb, 768, 2304, 18);
    // 6. V transpose
    vtrans_k<<<dim3(41, 2, 48), 256, 0, stream>>>(qkvb, vtb);
    // 7. attention -> ao (bf16, reuses patch buffer): balanced + LDS-staged, XCD-affine
    attn_k<<<528, 256, 0, stream>>>(qkvb, vtb, apao);
    // 8. output proj + residual -> tok
    gemm_k<64, 3><<<12 * 41, 256, 0, stream>>>(apao, wo_t, bo, tok, tok, 768, 768, 12);
    // 9. LN2 -> h
    ln_k<<<1296, 256, 0, stream>>>(tok, ln2g, ln2b, hbuf);
    // 10. MLP1 (relu) -> a1 (bf16)
    gemm_k<128, 2><<<24 * 41, 256, 0, stream>>>(hbuf, w1_t, b1, nullptr, a1, 768, 3072, 24);
    // 11. MLP2 + residual, store transposed (B,E,36,36) -> d_out (f32)
    gemm_k<64, 4><<<12 * 41, 256, 0, stream>>>(a1, w2_t, b2, tok, d_out, 3072, 768, 12);
}

// Round 6
// 338.289 us; speedup vs baseline: 1.2312x; 1.0369x over previous
//
#include <hip/hip_runtime.h>

typedef unsigned short u16;
typedef unsigned int u32;
typedef unsigned long long u64;
typedef float f32x4 __attribute__((ext_vector_type(4)));
typedef __bf16 bf16x8 __attribute__((ext_vector_type(8)));
typedef __bf16 bf16x4 __attribute__((ext_vector_type(4)));
typedef u16 u16x8 __attribute__((ext_vector_type(8)));

#define DEV __device__ __forceinline__

// ---- constants for this problem ----
// B=4, T=1296 (36x36 patches), E=768, H=12, HD=64, M = B*T = 5184
// patch K = C_IN*P*P = 3*16*16 = 768

DEV u16 f2bf(float f) {
    union { float f; u32 u; } un; un.f = f;
    u32 u = un.u;
    return (u16)((u + 0x7fffu + ((u >> 16) & 1u)) >> 16);
}

DEV void gll16(const u16* src, u16* dst) {
    auto g = (const __attribute__((address_space(1))) u32*)(src);
    auto s = (__attribute__((address_space(3))) u32*)(dst);
    __builtin_amdgcn_global_load_lds(g, s, 16, 0, 0);
}

// ---------------- weight convert / transpose ----------------
__global__ void convcvt_k(const float* __restrict__ src, u16* __restrict__ dst) {
    int i = blockIdx.x * 256 + threadIdx.x;          // one float4 per thread
    f32x4 v = ((const f32x4*)src)[i];
    union { u16 q[4]; u64 ll; } un;
    #pragma unroll
    for (int j = 0; j < 4; ++j) un.q[j] = f2bf(v[j]);
    ((u64*)dst)[i] = un.ll;
}

// src: f32 [K][N] row-major; dst: bf16 [N][K]
__global__ void wtrans_k(const float* __restrict__ src, u16* __restrict__ dst, int K, int N) {
    __shared__ float tile[32][33];
    int n0 = blockIdx.x * 32, k0 = blockIdx.y * 32;
    int tx = threadIdx.x & 31, ty = threadIdx.x >> 5;   // 32 x 8
    #pragma unroll
    for (int i = 0; i < 32; i += 8)
        tile[ty + i][tx] = src[(size_t)(k0 + ty + i) * N + n0 + tx];
    __syncthreads();
    #pragma unroll
    for (int i = 0; i < 32; i += 8)
        dst[(size_t)(n0 + ty + i) * K + k0 + tx] = f2bf(tile[tx][ty + i]);
}

// ---------------- patch gather: x (B,3,576,576) -> A [5184][768] bf16 ----------------
__global__ void patch_k(const float* __restrict__ x, u16* __restrict__ out) {
    int idx = blockIdx.x * 256 + threadIdx.x;   // [b][c][i][p][j], j innermost
    int j = idx % 36; int r1 = idx / 36;
    int p = r1 % 16;  int r2 = r1 / 16;
    int i = r2 % 36;  int r3 = r2 / 36;
    int c = r3 % 3;   int b = r3 / 3;
    const f32x4* src = (const f32x4*)(x + (size_t)((b * 3 + c) * 576 + i * 16 + p) * 576 + j * 16);
    u16x8 lo, hi;
    #pragma unroll
    for (int k = 0; k < 2; ++k) {
        f32x4 v = src[k];
        #pragma unroll
        for (int e = 0; e < 4; ++e) lo[k * 4 + e] = f2bf(v[e]);
    }
    #pragma unroll
    for (int k = 0; k < 2; ++k) {
        f32x4 v = src[2 + k];
        #pragma unroll
        for (int e = 0; e < 4; ++e) hi[k * 4 + e] = f2bf(v[e]);
    }
    u16* dst = out + (size_t)(b * 1296 + i * 36 + j) * 768 + c * 256 + p * 16;
    *(u16x8*)dst = lo;
    *(u16x8*)(dst + 8) = hi;
}

// ---------------- LayerNorm: f32 [5184][768] -> bf16 [5184][768] ----------------
__global__ __launch_bounds__(256) void ln_k(const float* __restrict__ x, const float* __restrict__ g,
                                            const float* __restrict__ bta, u16* __restrict__ out) {
    int row = blockIdx.x * 4 + (threadIdx.x >> 6);
    int l = threadIdx.x & 63;
    const float* xr = x + (size_t)row * 768;
    float v[12]; float s = 0.f, s2 = 0.f;
    #pragma unroll
    for (int i = 0; i < 12; ++i) { v[i] = xr[l + 64 * i]; s += v[i]; s2 += v[i] * v[i]; }
    #pragma unroll
    for (int off = 32; off; off >>= 1) { s += __shfl_xor(s, off); s2 += __shfl_xor(s2, off); }
    float mu = s * (1.f / 768.f);
    float var = s2 * (1.f / 768.f) - mu * mu;
    float rs = rsqrtf(var + 1e-5f);
    u16* orow = out + (size_t)row * 768;
    #pragma unroll
    for (int i = 0; i < 12; ++i) {
        int c = l + 64 * i;
        orow[c] = f2bf((v[i] - mu) * rs * g[c] + bta[c]);
    }
}

// ---------------- V transpose: qkv[.][1536+h*64+d] -> vt[bh][d][t] (t padded to 1344) ----------------
__global__ void vtrans_k(const u16* __restrict__ qkv, u16* __restrict__ vt) {
    __shared__ u16 tile[32][33];
    int bh = blockIdx.z; int b = bh / 12, h = bh % 12;
    int t0 = blockIdx.x * 32, d0 = blockIdx.y * 32;
    int tx = threadIdx.x & 31, ty = threadIdx.x >> 5;
    #pragma unroll
    for (int i = 0; i < 32; i += 8) {
        int t = t0 + ty + i; int tc = min(t, 1295);
        tile[ty + i][tx] = qkv[(size_t)(b * 1296 + tc) * 2304 + 1536 + h * 64 + d0 + tx];
    }
    __syncthreads();
    #pragma unroll
    for (int i = 0; i < 32; i += 8) {
        int d = d0 + ty + i; int t = t0 + tx;
        if (t < 1296) vt[(size_t)(bh * 64 + d) * 1344 + t] = tile[tx][ty + i];
    }
}

// ---------------- GEMM v2: C[M][N] = A[M][K] @ Bt[N][K]^T (+epilogue) ----------------
// BK=64 (128B LDS rows, full 32-bank span), piece^(row&7) swizzle (2-way max conflicts),
// 1D grid with bijective XCD-chunked decode (col-block fastest within an XCD).
// EPI: 0 = +bias, f32 store        (patch embed -> tok)
//      1 = bf16 store, no bias     (qkv)
//      2 = +bias, relu, bf16 store (mlp1 -> a1)
//      3 = +bias, +resid, f32 store(proj -> tok)
//      4 = +bias, +resid, f32 store TRANSPOSED to (B,E,T)   (mlp2 -> d_out)
template <int BN, int EPI>
__global__ __launch_bounds__(256) void gemm_k(const u16* __restrict__ A, const u16* __restrict__ Bt,
                                              const float* __restrict__ bias, const float* __restrict__ resid,
                                              void* __restrict__ Cout, int K, int ldc, int nbx) {
    constexpr int M = 5184;
    constexpr int NF = BN / 32;
    // [buf][(128 A-rows + BN B-rows) x 64 u16 (128B)]
    __shared__ __align__(16) u16 lds[2][(128 + BN) * 64];
    const int tid = threadIdx.x;
    const int l = tid & 63, w = tid >> 6;
    const int lr = l & 15, lq = l >> 4;
    const int wm = w >> 1, wn = w & 1;

    // bijective XCD-chunked decode: ids on XCD x are {x, x+8, ...}; chunk start x*q+min(x,r)
    const int total = nbx * 41;
    const int q = total >> 3, r = total & 7;
    const int x = blockIdx.x & 7;
    const int j = blockIdx.x >> 3;
    const int wrk = x * q + min(x, r) + j;
    const int by = wrk / nbx, bx = wrk - by * nbx;
    const int bm = by * 128;
    const int bn = bx * BN;

    f32x4 acc[4][NF];
    f32x4 zz = {0.f, 0.f, 0.f, 0.f};
    #pragma unroll
    for (int i = 0; i < 4; ++i)
        #pragma unroll
        for (int jj = 0; jj < NF; ++jj) acc[i][jj] = zz;

    const int nk = K >> 6;

    // stage A (128x64) + B (BNx64) for k-chunk kt into buffer buf.
    // 16B slot s=(row,piece): LDS linear, global source piece = piece^(row&7).
    auto stage = [&](int buf, int kt) {
        u16* abase = &lds[buf][0];
        #pragma unroll
        for (int i = 0; i < 4; ++i) {
            int slot = tid + i * 256;
            int row = slot >> 3, piece = slot & 7;
            int sp = piece ^ (row & 7);
            const u16* src = A + (size_t)min(bm + row, M - 1) * K + kt * 64 + sp * 8;
            gll16(src, abase + ((tid & ~63) + i * 256) * 8);
        }
        u16* bbase = &lds[buf][128 * 64];
        #pragma unroll
        for (int i = 0; i < NF; ++i) {
            int slot = tid + i * 256;
            int row = slot >> 3, piece = slot & 7;
            int sp = piece ^ (row & 7);
            const u16* src = Bt + (size_t)(bn + row) * K + kt * 64 + sp * 8;
            gll16(src, bbase + ((tid & ~63) + i * 256) * 8);
        }
    };

    stage(0, 0);
    __syncthreads();
    for (int kt = 0; kt < nk; ++kt) {
        int cur = kt & 1;
        if (kt + 1 < nk) stage(cur ^ 1, kt + 1);
        bf16x8 af[4][2], bfr[NF][2];
        #pragma unroll
        for (int mi = 0; mi < 4; ++mi) {
            int row = wm * 64 + mi * 16 + lr;
            #pragma unroll
            for (int ks = 0; ks < 2; ++ks)
                af[mi][ks] = *(const bf16x8*)&lds[cur][row * 64 + (((lq + 4 * ks) ^ (row & 7)) << 3)];
        }
        #pragma unroll
        for (int ni = 0; ni < NF; ++ni) {
            int row = wn * (BN / 2) + ni * 16 + lr;
            #pragma unroll
            for (int ks = 0; ks < 2; ++ks)
                bfr[ni][ks] = *(const bf16x8*)&lds[cur][128 * 64 + row * 64 + (((lq + 4 * ks) ^ (row & 7)) << 3)];
        }
        #pragma unroll
        for (int mi = 0; mi < 4; ++mi)
            #pragma unroll
            for (int ni = 0; ni < NF; ++ni) {
                acc[mi][ni] = __builtin_amdgcn_mfma_f32_16x16x32_bf16(af[mi][0], bfr[ni][0], acc[mi][ni], 0, 0, 0);
                acc[mi][ni] = __builtin_amdgcn_mfma_f32_16x16x32_bf16(af[mi][1], bfr[ni][1], acc[mi][ni], 0, 0, 0);
            }
        __syncthreads();
    }

    // epilogue: D element (row = 4*lq + r within 16-tile, col = lr)
    #pragma unroll
    for (int mi = 0; mi < 4; ++mi) {
        #pragma unroll
        for (int ni = 0; ni < NF; ++ni) {
            int col = bn + wn * (BN / 2) + ni * 16 + lr;
            float bv = 0.f;
            if constexpr (EPI != 1) bv = bias[col];
            #pragma unroll
            for (int rr = 0; rr < 4; ++rr) {
                int m = bm + wm * 64 + mi * 16 + 4 * lq + rr;
                if (m < M) {
                    float v = acc[mi][ni][rr] + bv;
                    if constexpr (EPI == 2) v = fmaxf(v, 0.f);
                    if constexpr (EPI == 3 || EPI == 4) v += resid[(size_t)m * ldc + col];
                    if constexpr (EPI == 0 || EPI == 3) {
                        ((float*)Cout)[(size_t)m * ldc + col] = v;
                    } else if constexpr (EPI == 4) {
                        int b = m / 1296, t = m - b * 1296;
                        ((float*)Cout)[(size_t)(b * 768 + col) * 1296 + t] = v;
                    } else {
                        ((u16*)Cout)[(size_t)m * ldc + col] = f2bf(v);
                    }
                }
            }
        }
    }
}

// ---------------- flash attention v4: swapped QK^T (lane-local q rows) ----------------
// 1D grid of 528 blocks; decode keeps all 11 blocks of a bh on one XCD (id%8 == bh%8).
// Wave-unit u = bx*4+wid in [0,40]: q-tiles q0S=16u (u<40) and q0L=16*(80-u).
// Per k-visit (KVBLK=64): K/V tiles double-buffered in LDS (global_load_lds, swizzled source).
// QK^T computed as mfma(K,Q): D col=lane&15 = q, row=4*lq+reg = k  ->  per-q softmax state
// is ONE scalar per lane; reduce = in-lane tree + shfl_xor(16)/(32); P->bf16 via cvt_pk pairs;
// PV as O^T = mfma(V^T, P^T) with unchanged fragment reads.
__global__ __launch_bounds__(256, 2) void attn_k(const u16* __restrict__ qkv, const u16* __restrict__ vt,
                                                 u16* __restrict__ ao) {
    const float SCALE = 0.03608439182435161f;   // 768^-0.5
    __shared__ __align__(16) u16 kv[2][2][4096]; // [buf][K/V][64 rows x 64 cols]
    __shared__ __align__(16) u16 plds[4][16 * 72];
    const int tid = threadIdx.x;
    const int wid = tid >> 6, l = tid & 63;
    // XCD-affinity decode: id%8 = bh%8
    const int id = blockIdx.x;
    const int xr = id & 7, sl = id >> 3;
    const int g = sl / 11, bx = sl - g * 11;
    const int bh = g * 8 + xr;
    const int b = bh / 12, h = bh % 12;
    const int uu = bx * 4 + wid;
    const int u = min(uu, 40);
    const bool valid = (uu <= 40);
    const int lr = l & 15, lq = l >> 4;
    const int q0S = 16 * u, q0L = 16 * (80 - u);
    const bool hasS = valid && (u < 40);
    const int nktS = (u < 40) ? (((q0S + 15) >> 6) + 1) : 0;
    const int nktL = ((q0L + 15) >> 6) + 1;
    const int umin = min(bx * 4, 40);
    const int nktmax = ((16 * (80 - umin) + 15) >> 6) + 1;

    const u16* kbase = qkv + (size_t)(b * 1296) * 2304 + 768 + h * 64;
    const u16* vbase = vt + (size_t)bh * 64 * 1344;
    u16* pl = &plds[wid][0];

    // Q fragments: row/col = q0+lr, contraction = d (same frag pattern for A and B roles)
    const u16* qpS = qkv + (size_t)(b * 1296 + q0S + lr) * 2304 + h * 64;
    const u16* qpL = qkv + (size_t)(b * 1296 + q0L + lr) * 2304 + h * 64;
    bf16x8 qS0 = *(const bf16x8*)(qpS + 8 * lq);
    bf16x8 qS1 = *(const bf16x8*)(qpS + 32 + 8 * lq);
    bf16x8 qL0 = *(const bf16x8*)(qpL + 8 * lq);
    bf16x8 qL1 = *(const bf16x8*)(qpL + 32 + 8 * lq);

    f32x4 zz = {0.f, 0.f, 0.f, 0.f};
    const float NEG = -__builtin_inff();
    f32x4 oS[4], oL[4];
    float mS = NEG, mL = NEG, lS = 0.f, lL = 0.f;
    #pragma unroll
    for (int i = 0; i < 4; ++i) { oS[i] = zz; oL[i] = zz; }

    // cooperative stage of K+V tiles for k0 = kt*64 into buffer `buf`.
    // global_load_lds dest = wave-uniform base + lane*16B; 512 slots per tile, wave w
    // section i covers slots i*256 + w*64 .. +63.  Linear LDS slot (row,piece) receives
    // global piece piece^(row&7) (source-side swizzle); readers apply the same XOR.
    auto stage = [&](int buf, int kt) {
        const int k0 = kt * 64;
        #pragma unroll
        for (int i = 0; i < 2; ++i) {
            int slot = tid + i * 256;      // 0..511 : 16B slots
            int row = slot >> 3;           // k index 0..63
            int piece = slot & 7;
            int sp = piece ^ (row & 7);
            int tc = min(k0 + row, 1295);
            gll16(kbase + (size_t)tc * 2304 + sp * 8,
                  &kv[buf][0][((tid & 0xFFFFFFC0) + i * 256) * 8]);
        }
        #pragma unroll
        for (int i = 0; i < 2; ++i) {
            int slot = tid + i * 256;
            int row = slot >> 3;           // d index 0..63
            int piece = slot & 7;
            int sp = piece ^ (row & 7);
            gll16(vbase + (size_t)row * 1344 + k0 + sp * 8,
                  &kv[buf][1][((tid & 0xFFFFFFC0) + i * 256) * 8]);
        }
    };

    bf16x8 kb[4][2], vb[4][2];

    auto visit = [&](int q0, bf16x8 qa0, bf16x8 qa1, f32x4 (&o)[4],
                     float& mrow, float& lsum, int k0) {
        const int qrow = q0 + lr;          // this lane's q row
        f32x4 s[4];
        __builtin_amdgcn_s_setprio(1);
        #pragma unroll
        for (int nt = 0; nt < 4; ++nt) {
            f32x4 a = zz;
            a = __builtin_amdgcn_mfma_f32_16x16x32_bf16(kb[nt][0], qa0, a, 0, 0, 0);
            a = __builtin_amdgcn_mfma_f32_16x16x32_bf16(kb[nt][1], qa1, a, 0, 0, 0);
            s[nt] = a;
        }
        __builtin_amdgcn_s_setprio(0);
        // mask (raw scores) + in-lane max tree
        float mnt[4];
        #pragma unroll
        for (int nt = 0; nt < 4; ++nt) {
            #pragma unroll
            for (int r = 0; r < 4; ++r) {
                int k = k0 + nt * 16 + 4 * lq + r;
                s[nt][r] = (k <= qrow) ? s[nt][r] : NEG;
            }
            mnt[nt] = fmaxf(fmaxf(s[nt][0], s[nt][1]), fmaxf(s[nt][2], s[nt][3]));
        }
        float mx = fmaxf(fmaxf(mnt[0], mnt[1]), fmaxf(mnt[2], mnt[3]));
        mx = fmaxf(mx, __shfl_xor(mx, 16));
        mx = fmaxf(mx, __shfl_xor(mx, 32));
        float nm = fmaxf(mrow, mx);
        float alpha = __expf(SCALE * (mrow - nm));
        mrow = nm;
        float nbase = -SCALE * nm;
        float tnt[4];
        #pragma unroll
        for (int nt = 0; nt < 4; ++nt) {
            #pragma unroll
            for (int r = 0; r < 4; ++r) {
                float p = __expf(fmaf(s[nt][r], SCALE, nbase));   // masked -inf -> 0
                s[nt][r] = p;
            }
            tnt[nt] = (s[nt][0] + s[nt][1]) + (s[nt][2] + s[nt][3]);
        }
        float ts = (tnt[0] + tnt[1]) + (tnt[2] + tnt[3]);
        ts += __shfl_xor(ts, 16);
        ts += __shfl_xor(ts, 32);
        lsum = lsum * alpha + ts;
        #pragma unroll
        for (int dt = 0; dt < 4; ++dt) o[dt] *= alpha;
        // P^T store: lane q=lr owns row lr; 4 consecutive k per reg-quad -> one 8B write per nt
        #pragma unroll
        for (int nt = 0; nt < 4; ++nt) {
            bf16x4 pv = __builtin_convertvector(s[nt], bf16x4);
            *(bf16x4*)&pl[lr * 72 + nt * 16 + 4 * lq] = pv;
        }
        __builtin_amdgcn_wave_barrier();
        bf16x8 pa0 = *(const bf16x8*)&pl[lr * 72 + 8 * lq];
        bf16x8 pa1 = *(const bf16x8*)&pl[lr * 72 + 32 + 8 * lq];
        __builtin_amdgcn_s_setprio(1);
        #pragma unroll
        for (int dt = 0; dt < 4; ++dt) {
            o[dt] = __builtin_amdgcn_mfma_f32_16x16x32_bf16(vb[dt][0], pa0, o[dt], 0, 0, 0);
            o[dt] = __builtin_amdgcn_mfma_f32_16x16x32_bf16(vb[dt][1], pa1, o[dt], 0, 0, 0);
        }
        __builtin_amdgcn_s_setprio(0);
        __builtin_amdgcn_wave_barrier();  // protect P buffer before next overwrite
    };

    stage(0, 0);
    for (int kt = 0; kt < nktmax; ++kt) {
        const int cur = kt & 1;
        const int k0 = kt * 64;
        __syncthreads();                       // stage(cur) complete; prior reads of cur^1 done
        if (kt + 1 < nktmax) stage(cur ^ 1, kt + 1);
        // load K/V fragments from LDS (swizzled read)
        #pragma unroll
        for (int nt = 0; nt < 4; ++nt) {
            int krow = nt * 16 + lr;
            kb[nt][0] = *(const bf16x8*)&kv[cur][0][krow * 64 + ((lq ^ (krow & 7)) << 3)];
            kb[nt][1] = *(const bf16x8*)&kv[cur][0][krow * 64 + (((lq + 4) ^ (krow & 7)) << 3)];
        }
        #pragma unroll
        for (int dt = 0; dt < 4; ++dt) {
            int vrow = dt * 16 + lr;
            vb[dt][0] = *(const bf16x8*)&kv[cur][1][vrow * 64 + ((lq ^ (vrow & 7)) << 3)];
            vb[dt][1] = *(const bf16x8*)&kv[cur][1][vrow * 64 + (((lq + 4) ^ (vrow & 7)) << 3)];
        }
        if (valid && kt < nktS) visit(q0S, qS0, qS1, oS, mS, lS, k0);
        if (valid && kt < nktL) visit(q0L, qL0, qL1, oL, mL, lL, k0);
    }

    if (valid) {
        // O^T layout: lane holds q=q0+lr, d = dt*16 + 4*lq + r  -> 8B packed stores
        if (hasS) {
            float inv = 1.f / lS;
            u16* aoS = ao + (size_t)(b * 1296 + q0S + lr) * 768 + h * 64 + 4 * lq;
            #pragma unroll
            for (int dt = 0; dt < 4; ++dt) {
                f32x4 ov = oS[dt] * inv;
                *(bf16x4*)(aoS + dt * 16) = __builtin_convertvector(ov, bf16x4);
            }
        }
        float invL = 1.f / lL;
        u16* aoL = ao + (size_t)(b * 1296 + q0L + lr) * 768 + h * 64 + 4 * lq;
        #pragma unroll
        for (int dt = 0; dt < 4; ++dt) {
            f32x4 ov = oL[dt] * invL;
            *(bf16x4*)(aoL + dt * 16) = __builtin_convertvector(ov, bf16x4);
        }
    }
}

extern "C" void kernel_launch(void* const* d_in, const int* in_sizes, int n_in,
                              void* d_out, int out_size, void* d_ws, size_t ws_size,
                              hipStream_t stream) {
    const float* x      = (const float*)d_in[0];
    const float* conv_w = (const float*)d_in[1];
    const float* conv_b = (const float*)d_in[2];
    const float* wq     = (const float*)d_in[3];
    const float* wk     = (const float*)d_in[4];
    const float* wv     = (const float*)d_in[5];
    const float* wo     = (const float*)d_in[6];
    const float* bo     = (const float*)d_in[7];
    const float* w1     = (const float*)d_in[8];
    const float* b1     = (const float*)d_in[9];
    const float* w2     = (const float*)d_in[10];
    const float* b2     = (const float*)d_in[11];
    const float* ln1g   = (const float*)d_in[12];
    const float* ln1b   = (const float*)d_in[13];
    const float* ln2g   = (const float*)d_in[14];
    const float* ln2b   = (const float*)d_in[15];

    char* ws = (char*)d_ws;
    size_t off = 0;
    auto alloc = [&](size_t bytes) { char* p = ws + off; off = (off + bytes + 255) & ~(size_t)255; return p; };
    u16*   convw_bf = (u16*)alloc((size_t)768 * 768 * 2);
    u16*   wqkv_t   = (u16*)alloc((size_t)2304 * 768 * 2);
    u16*   wo_t     = (u16*)alloc((size_t)768 * 768 * 2);
    u16*   w1_t     = (u16*)alloc((size_t)3072 * 768 * 2);
    u16*   w2_t     = (u16*)alloc((size_t)768 * 3072 * 2);
    float* tok      = (float*)alloc((size_t)5184 * 768 * 4);
    u16*   hbuf     = (u16*)alloc((size_t)5184 * 768 * 2);
    u16*   apao     = (u16*)alloc((size_t)5184 * 768 * 2);   // patches, later attention output
    size_t qkv_bytes = ((size_t)5184 * 2304 * 2 + 255) & ~(size_t)255;
    size_t vt_bytes  = (size_t)48 * 64 * 1344 * 2;
    size_t a1_bytes  = (size_t)5184 * 3072 * 2;
    size_t big_bytes = qkv_bytes + vt_bytes;
    if (a1_bytes > big_bytes) big_bytes = a1_bytes;
    char* big = alloc(big_bytes);
    u16* qkvb = (u16*)big;
    u16* vtb  = (u16*)(big + qkv_bytes);
    u16* a1   = (u16*)big;   // overlays qkv+vt (dead after attention)

    // 1. weight prep
    convcvt_k<<<576, 256, 0, stream>>>(conv_w, convw_bf);
    wtrans_k<<<dim3(24, 24), 256, 0, stream>>>(wq, wqkv_t, 768, 768);
    wtrans_k<<<dim3(24, 24), 256, 0, stream>>>(wk, wqkv_t + 768 * 768, 768, 768);
    wtrans_k<<<dim3(24, 24), 256, 0, stream>>>(wv, wqkv_t + 2 * 768 * 768, 768, 768);
    wtrans_k<<<dim3(24, 24), 256, 0, stream>>>(wo, wo_t, 768, 768);
    wtrans_k<<<dim3(96, 24), 256, 0, stream>>>(w1, w1_t, 768, 3072);
    wtrans_k<<<dim3(24, 96), 256, 0, stream>>>(w2, w2_t, 3072, 768);
    // 2. patch gather
    patch_k<<<972, 256, 0, stream>>>(x, apao);
    // 3. patch-embed GEMM -> tok (f32)
    gemm_k<64, 0><<<12 * 41, 256, 0, stream>>>(apao, convw_bf, conv_b, nullptr, tok, 768, 768, 12);
    // 4. LN1 -> h (bf16)
    ln_k<<<1296, 256, 0, stream>>>(tok, ln1g, ln1b, hbuf);
    // 5. fused QKV GEMM -> qkv (bf16)
    gemm_k<128, 1><<<18 * 41, 256, 0, stream>>>(hbuf, wqkv_t, nullptr, nullptr, qkvb, 768, 2304, 18);
    // 6. V transpose
    vtrans_k<<<dim3(41, 2, 48), 256, 0, stream>>>(qkvb, vtb);
    // 7. attention -> ao (bf16, reuses patch buffer): balanced + LDS-staged, XCD-affine, swapped-QK
    attn_k<<<528, 256, 0, stream>>>(qkvb, vtb, apao);
    // 8. output proj + residual -> tok
    gemm_k<64, 3><<<12 * 41, 256, 0, stream>>>(apao, wo_t, bo, tok, tok, 768, 768, 12);
    // 9. LN2 -> h
    ln_k<<<1296, 256, 0, stream>>>(tok, ln2g, ln2b, hbuf);
    // 10. MLP1 (relu) -> a1 (bf16)
    gemm_k<128, 2><<<24 * 41, 256, 0, stream>>>(hbuf, w1_t, b1, nullptr, a1, 768, 3072, 24);
    // 11. MLP2 + residual, store transposed (B,E,36,36) -> d_out (f32)
    gemm_k<64, 4><<<12 * 41, 256, 0, stream>>>(a1, w2_t, b2, tok, d_out, 3072, 768, 12);
}